// Round 1
// baseline (7779.234 us; speedup 1.0000x reference)
//
#include <hip/hip_runtime.h>
#include <math.h>

#define D_MODEL 1024
#define NUM_HEADS 16
#define HEAD_SIZE 64
#define SEQ_T 2048

// ---------------- RMSNorm: one block per row ----------------
__global__ __launch_bounds__(256) void rmsnorm_kernel(const float* __restrict__ x,
                                                      const float* __restrict__ scale,
                                                      float* __restrict__ out) {
    __shared__ float red[4];
    int row = blockIdx.x;
    const float* xp = x + (size_t)row * D_MODEL;
    float* op = out + (size_t)row * D_MODEL;
    int tid = threadIdx.x;
    float s = 0.f;
    for (int i = tid; i < D_MODEL; i += 256) { float v = xp[i]; s += v * v; }
    for (int off = 32; off; off >>= 1) s += __shfl_down(s, off);
    if ((tid & 63) == 0) red[tid >> 6] = s;
    __syncthreads();
    if (tid == 0) red[0] = red[0] + red[1] + red[2] + red[3];
    __syncthreads();
    float inv = rsqrtf(red[0] * (1.0f / D_MODEL) + 1e-6f);
    for (int i = tid; i < D_MODEL; i += 256) op[i] = xp[i] * inv * scale[i];
}

// ---------------- RoPE: interleaved pairs, one thread per pair ----------------
__global__ __launch_bounds__(256) void rope_kernel(const float* __restrict__ x,
                                                   float* __restrict__ out,
                                                   int total_pairs) {
    int p = blockIdx.x * 256 + threadIdx.x;
    if (p >= total_pairs) return;
    int i = p & 31;            // half-dim index (0..31)
    int rem = p >> 5;          // (b*T + t)*H + h
    int rem2 = rem >> 4;       // b*T + t
    int t = rem2 & (SEQ_T - 1);
    size_t base = (size_t)rem * HEAD_SIZE + 2 * i;
    // theta_i = 10000^(-i/32) ; ln(10000)/32 = 0.2878231366242557
    float theta = expf(-0.2878231366242557f * (float)i);
    float ang = (float)t * theta;
    float sv, cv;
    sincosf(ang, &sv, &cv);
    float x0 = x[base], x1 = x[base + 1];
    out[base]     = x0 * cv - x1 * sv;
    out[base + 1] = x1 * cv + x0 * sv;
}

// ---------------- Tiled fp32 GEMM: C[M,N] = act(A[M,K] @ W[N,K]^T + bias) (+C) ----------------
// 64x64 tile, TK=16, 256 threads, 4x4 register block per thread.
template <int ACT, bool ADD_OUT>
__global__ __launch_bounds__(256) void gemm_kernel(const float* __restrict__ A,
                                                   const float* __restrict__ W,
                                                   const float* __restrict__ bias,
                                                   float* __restrict__ C,
                                                   int M, int N, int K) {
    __shared__ float As[16][65];
    __shared__ float Ws[16][65];
    int tid = threadIdx.x;
    int tx = tid & 15, ty = tid >> 4;
    int m0 = blockIdx.y * 64, n0 = blockIdx.x * 64;
    float acc[4][4] = {};
    int kk = tid & 15;
    int rr = tid >> 4;
    for (int k0 = 0; k0 < K; k0 += 16) {
#pragma unroll
        for (int p = 0; p < 4; p++) {
            int r = rr + 16 * p;
            As[kk][r] = A[(size_t)(m0 + r) * K + k0 + kk];
            Ws[kk][r] = W[(size_t)(n0 + r) * K + k0 + kk];
        }
        __syncthreads();
#pragma unroll
        for (int k = 0; k < 16; k++) {
            float a[4], b[4];
#pragma unroll
            for (int i = 0; i < 4; i++) a[i] = As[k][ty * 4 + i];
#pragma unroll
            for (int j = 0; j < 4; j++) b[j] = Ws[k][tx * 4 + j];
#pragma unroll
            for (int i = 0; i < 4; i++)
#pragma unroll
                for (int j = 0; j < 4; j++) acc[i][j] += a[i] * b[j];
        }
        __syncthreads();
    }
#pragma unroll
    for (int i = 0; i < 4; i++) {
        int m = m0 + ty * 4 + i;
#pragma unroll
        for (int j = 0; j < 4; j++) {
            int n = n0 + tx * 4 + j;
            float v = acc[i][j] + bias[n];
            if (ACT == 1) v = v / (1.f + expf(-v));  // silu
            size_t idx = (size_t)m * N + n;
            if (ADD_OUT) v += C[idx];
            C[idx] = v;
        }
    }
}

// ---------------- Causal attention: one block per (b, h, q-row) ----------------
__global__ __launch_bounds__(256) void attn_kernel(const float* __restrict__ Q,
                                                   const float* __restrict__ Kk,
                                                   const float* __restrict__ V,
                                                   float* __restrict__ O, int T) {
    __shared__ float sc[SEQ_T];
    __shared__ float qv[64];
    __shared__ float red[4];
    __shared__ float pv[4][64];
    int blk = blockIdx.x;
    int qi = blk % T;
    int bh = blk / T;
    int h = bh % NUM_HEADS;
    int b = bh / NUM_HEADS;
    int tid = threadIdx.x;
    size_t rowq = ((size_t)(b * T + qi)) * D_MODEL + h * HEAD_SIZE;
    if (tid < 64) qv[tid] = Q[rowq + tid];
    __syncthreads();
    int L = qi + 1;
    for (int t = tid; t < L; t += 256) {
        const float* kp = Kk + ((size_t)(b * T + t)) * D_MODEL + h * HEAD_SIZE;
        float s = 0.f;
#pragma unroll
        for (int d = 0; d < 64; d++) s += qv[d] * kp[d];
        sc[t] = s * 0.125f;  // 1/sqrt(64)
    }
    __syncthreads();
    // row max
    float m = -1e30f;
    for (int t = tid; t < L; t += 256) m = fmaxf(m, sc[t]);
    for (int off = 32; off; off >>= 1) m = fmaxf(m, __shfl_down(m, off));
    if ((tid & 63) == 0) red[tid >> 6] = m;
    __syncthreads();
    if (tid == 0) red[0] = fmaxf(fmaxf(red[0], red[1]), fmaxf(red[2], red[3]));
    __syncthreads();
    m = red[0];
    // exp + sum
    float ssum = 0.f;
    for (int t = tid; t < L; t += 256) {
        float e = expf(sc[t] - m);
        sc[t] = e;
        ssum += e;
    }
    __syncthreads();  // sc writes visible; red safe to reuse
    for (int off = 32; off; off >>= 1) ssum += __shfl_down(ssum, off);
    if ((tid & 63) == 0) red[tid >> 6] = ssum;
    __syncthreads();
    if (tid == 0) red[0] = red[0] + red[1] + red[2] + red[3];
    __syncthreads();
    float inv = 1.f / red[0];
    // PV: 4 chunks of t, 64 dims
    int d = tid & 63, c = tid >> 6;
    float acc = 0.f;
    for (int t = c; t < L; t += 4)
        acc += sc[t] * V[((size_t)(b * T + t)) * D_MODEL + h * HEAD_SIZE + d];
    pv[c][d] = acc;
    __syncthreads();
    if (tid < 64) {
        float o = (pv[0][tid] + pv[1][tid] + pv[2][tid] + pv[3][tid]) * inv;
        O[rowq + tid] = o;
    }
}

extern "C" void kernel_launch(void* const* d_in, const int* in_sizes, int n_in,
                              void* d_out, int out_size, void* d_ws, size_t ws_size,
                              hipStream_t stream) {
    const float* x          = (const float*)d_in[0];
    const float* rms_scale  = (const float*)d_in[1];
    const float* in_proj_w  = (const float*)d_in[2];
    const float* in_proj_b  = (const float*)d_in[3];
    const float* out_proj_w = (const float*)d_in[4];
    const float* out_proj_b = (const float*)d_in[5];
    const float* w1         = (const float*)d_in[6];
    const float* b1         = (const float*)d_in[7];
    const float* w2         = (const float*)d_in[8];
    const float* b2         = (const float*)d_in[9];
    float* out = (float*)d_out;

    const int rows = in_sizes[0] / D_MODEL;  // B*T = 4096
    const int T = SEQ_T;
    const int B = rows / T;
    const size_t R = (size_t)rows * D_MODEL;  // 4M floats

    float* ws = (float*)d_ws;
    float* XN  = ws;            // xn; later CTX; later YN
    float* RP  = ws + R;        // roped xn; later H1 (spans RP..RP+4R)
    float* Qb  = ws + 2 * R;
    float* Kb  = ws + 3 * R;
    float* Vb  = ws + 4 * R;
    float* CTX = XN;
    float* YN  = XN;
    float* H1  = RP;            // rows*4096 floats

    // 1. xn = rmsnorm(x)
    rmsnorm_kernel<<<rows, 256, 0, stream>>>(x, rms_scale, XN);
    // 2. RP = rope(xn)   (q_in == k_in in the reference)
    int total_pairs = rows * NUM_HEADS * (HEAD_SIZE / 2);
    rope_kernel<<<(total_pairs + 255) / 256, 256, 0, stream>>>(XN, RP, total_pairs);
    // 3-5. Q, K, V projections
    {
        dim3 g(D_MODEL / 64, rows / 64);
        gemm_kernel<0, false><<<g, 256, 0, stream>>>(RP, in_proj_w, in_proj_b, Qb,
                                                     rows, D_MODEL, D_MODEL);
        gemm_kernel<0, false><<<g, 256, 0, stream>>>(RP, in_proj_w + (size_t)D_MODEL * D_MODEL,
                                                     in_proj_b + D_MODEL, Kb,
                                                     rows, D_MODEL, D_MODEL);
        gemm_kernel<0, false><<<g, 256, 0, stream>>>(XN, in_proj_w + 2 * (size_t)D_MODEL * D_MODEL,
                                                     in_proj_b + 2 * D_MODEL, Vb,
                                                     rows, D_MODEL, D_MODEL);
    }
    // 6. attention -> CTX
    attn_kernel<<<B * NUM_HEADS * T, 256, 0, stream>>>(Qb, Kb, Vb, CTX, T);
    // 7. y = CTX @ out_proj_w^T + b  -> d_out
    {
        dim3 g(D_MODEL / 64, rows / 64);
        gemm_kernel<0, false><<<g, 256, 0, stream>>>(CTX, out_proj_w, out_proj_b, out,
                                                     rows, D_MODEL, D_MODEL);
    }
    // 8. yn = rmsnorm(y)
    rmsnorm_kernel<<<rows, 256, 0, stream>>>(out, rms_scale, YN);
    // 9. H1 = silu(yn @ w1^T + b1)
    {
        dim3 g(4 * D_MODEL / 64, rows / 64);
        gemm_kernel<1, false><<<g, 256, 0, stream>>>(YN, w1, b1, H1,
                                                     rows, 4 * D_MODEL, D_MODEL);
    }
    // 10. out += H1 @ w2^T + b2
    {
        dim3 g(D_MODEL / 64, rows / 64);
        gemm_kernel<0, true><<<g, 256, 0, stream>>>(H1, w2, b2, out,
                                                    rows, D_MODEL, 4 * D_MODEL);
    }
}

// Round 2
// 2919.815 us; speedup vs baseline: 2.6643x; 2.6643x over previous
//
#include <hip/hip_runtime.h>
#include <math.h>

#define D_MODEL 1024
#define NUM_HEADS 16
#define HEAD_SIZE 64
#define SEQ_T 2048
#define BM 64
#define BN 64

// ---------------- RMSNorm: one block per row ----------------
__global__ __launch_bounds__(256) void rmsnorm_kernel(const float* __restrict__ x,
                                                      const float* __restrict__ scale,
                                                      float* __restrict__ out) {
    __shared__ float red[4];
    int row = blockIdx.x;
    const float* xp = x + (size_t)row * D_MODEL;
    float* op = out + (size_t)row * D_MODEL;
    int tid = threadIdx.x;
    float s = 0.f;
    for (int i = tid; i < D_MODEL; i += 256) { float v = xp[i]; s += v * v; }
    for (int off = 32; off; off >>= 1) s += __shfl_down(s, off);
    if ((tid & 63) == 0) red[tid >> 6] = s;
    __syncthreads();
    if (tid == 0) red[0] = red[0] + red[1] + red[2] + red[3];
    __syncthreads();
    float inv = rsqrtf(red[0] * (1.0f / D_MODEL) + 1e-6f);
    for (int i = tid; i < D_MODEL; i += 256) op[i] = xp[i] * inv * scale[i];
}

// ---------------- RoPE: interleaved pairs, one thread per pair ----------------
__global__ __launch_bounds__(256) void rope_kernel(const float* __restrict__ x,
                                                   float* __restrict__ out,
                                                   int total_pairs) {
    int p = blockIdx.x * 256 + threadIdx.x;
    if (p >= total_pairs) return;
    int i = p & 31;            // half-dim index (0..31)
    int rem = p >> 5;          // (b*T + t)*H + h
    int rem2 = rem >> 4;       // b*T + t
    int t = rem2 & (SEQ_T - 1);
    size_t base = (size_t)rem * HEAD_SIZE + 2 * i;
    float theta = expf(-0.2878231366242557f * (float)i);  // ln(10000)/32
    float ang = (float)t * theta;
    float sv, cv;
    sincosf(ang, &sv, &cv);
    float x0 = x[base], x1 = x[base + 1];
    out[base]     = x0 * cv - x1 * sv;
    out[base + 1] = x1 * cv + x0 * sv;
}

// ---------------- Tiled fp32 GEMM: C[M,N] = act(A[M,K] @ W[N,K]^T + bias) (+C) ----------------
template <int ACT, bool ADD_OUT>
__global__ __launch_bounds__(256) void gemm_kernel(const float* __restrict__ A,
                                                   const float* __restrict__ W,
                                                   const float* __restrict__ bias,
                                                   float* __restrict__ C,
                                                   int M, int N, int K) {
    __shared__ float As[16][65];
    __shared__ float Ws[16][65];
    int tid = threadIdx.x;
    int tx = tid & 15, ty = tid >> 4;
    int m0 = blockIdx.y * 64, n0 = blockIdx.x * 64;
    float acc[4][4] = {};
    int kk = tid & 15;
    int rr = tid >> 4;
    for (int k0 = 0; k0 < K; k0 += 16) {
#pragma unroll
        for (int p = 0; p < 4; p++) {
            int r = rr + 16 * p;
            As[kk][r] = A[(size_t)(m0 + r) * K + k0 + kk];
            Ws[kk][r] = W[(size_t)(n0 + r) * K + k0 + kk];
        }
        __syncthreads();
#pragma unroll
        for (int k = 0; k < 16; k++) {
            float a[4], b[4];
#pragma unroll
            for (int i = 0; i < 4; i++) a[i] = As[k][ty * 4 + i];
#pragma unroll
            for (int j = 0; j < 4; j++) b[j] = Ws[k][tx * 4 + j];
#pragma unroll
            for (int i = 0; i < 4; i++)
#pragma unroll
                for (int j = 0; j < 4; j++) acc[i][j] += a[i] * b[j];
        }
        __syncthreads();
    }
#pragma unroll
    for (int i = 0; i < 4; i++) {
        int m = m0 + ty * 4 + i;
#pragma unroll
        for (int j = 0; j < 4; j++) {
            int n = n0 + tx * 4 + j;
            float v = acc[i][j] + bias[n];
            if (ACT == 1) v = v / (1.f + expf(-v));  // silu
            size_t idx = (size_t)m * N + n;
            if (ADD_OUT) v += C[idx];
            C[idx] = v;
        }
    }
}

// ---------------- Flash attention: one block per (b, h, 64-row q-tile) ----------------
// LDS: Qs/Ks dim-major [d][row] for b128 outer-product reads; Vs/Ps row-major.
// Exactly 64 KB static LDS (4 x 64x64 fp32) -> 2 blocks/CU.
__global__ __launch_bounds__(256) void attn_flash_kernel(const float* __restrict__ Qg,
                                                         const float* __restrict__ Kg,
                                                         const float* __restrict__ Vg,
                                                         float* __restrict__ Og, int T) {
    __shared__ float Qs[HEAD_SIZE][BM];  // [d][i]
    __shared__ float Ks[HEAD_SIZE][BN];  // [d][j]
    __shared__ float Vs[BN][HEAD_SIZE];  // [j][d]
    __shared__ float Ps[BM][BN];         // [i][j]

    int nqt = T / BM;  // 32
    int idx = blockIdx.x;
    int qt = (nqt - 1) - (idx % nqt);  // heavy tiles first
    int bh = idx / nqt;
    int h = bh % NUM_HEADS;
    int b = bh / NUM_HEADS;
    int tid = threadIdx.x;
    int tx = tid & 15, ty = tid >> 4;
    int q0 = qt * BM;

    const float* Qb = Qg + ((size_t)b * T) * D_MODEL + h * HEAD_SIZE;
    const float* Kb = Kg + ((size_t)b * T) * D_MODEL + h * HEAD_SIZE;
    const float* Vb = Vg + ((size_t)b * T) * D_MODEL + h * HEAD_SIZE;

    // loader mapping: 4 threads per row, 16 consecutive floats each (64B segments)
    int lr = tid >> 2;            // row 0..63
    int ld0 = (tid & 3) * 16;     // dim base

    // stage Q tile transposed
    {
        const float* src = Qb + (size_t)(q0 + lr) * D_MODEL + ld0;
#pragma unroll
        for (int qq = 0; qq < 4; qq++) {
            float4 v = *(const float4*)(src + qq * 4);
            int d = ld0 + qq * 4;
            Qs[d + 0][lr] = v.x;
            Qs[d + 1][lr] = v.y;
            Qs[d + 2][lr] = v.z;
            Qs[d + 3][lr] = v.w;
        }
    }

    float m_i[4], l_i[4], o[4][4];
#pragma unroll
    for (int i = 0; i < 4; i++) {
        m_i[i] = -1e30f;
        l_i[i] = 0.f;
#pragma unroll
        for (int j = 0; j < 4; j++) o[i][j] = 0.f;
    }

    for (int kt = 0; kt <= qt; kt++) {
        int k0 = kt * BN;
        __syncthreads();  // prev-tile LDS reads done; also makes Q visible on iter 0
        // stage K (transposed) and V (row-major)
        {
            const float* ksrc = Kb + (size_t)(k0 + lr) * D_MODEL + ld0;
            const float* vsrc = Vb + (size_t)(k0 + lr) * D_MODEL + ld0;
#pragma unroll
            for (int qq = 0; qq < 4; qq++) {
                float4 kv = *(const float4*)(ksrc + qq * 4);
                int d = ld0 + qq * 4;
                Ks[d + 0][lr] = kv.x;
                Ks[d + 1][lr] = kv.y;
                Ks[d + 2][lr] = kv.z;
                Ks[d + 3][lr] = kv.w;
            }
#pragma unroll
            for (int qq = 0; qq < 4; qq++) {
                float4 vv = *(const float4*)(vsrc + qq * 4);
                *(float4*)&Vs[lr][ld0 + qq * 4] = vv;
            }
        }
        __syncthreads();

        // S = (Q K^T) * scale, 4x4 per thread
        float s[4][4] = {};
#pragma unroll 8
        for (int d = 0; d < HEAD_SIZE; d++) {
            float4 qv = *(const float4*)&Qs[d][ty * 4];
            float4 kv = *(const float4*)&Ks[d][tx * 4];
            float qa[4] = {qv.x, qv.y, qv.z, qv.w};
            float ka[4] = {kv.x, kv.y, kv.z, kv.w};
#pragma unroll
            for (int i = 0; i < 4; i++)
#pragma unroll
                for (int j = 0; j < 4; j++) s[i][j] += qa[i] * ka[j];
        }
        bool diag = (kt == qt);
#pragma unroll
        for (int i = 0; i < 4; i++)
#pragma unroll
            for (int j = 0; j < 4; j++) {
                float v = s[i][j] * 0.125f;  // 1/sqrt(64)
                if (diag && (tx * 4 + j > ty * 4 + i)) v = -1e30f;
                s[i][j] = v;
            }

        // online softmax: rows owned by the 16 lanes sharing ty (contiguous in wave)
#pragma unroll
        for (int i = 0; i < 4; i++) {
            float mn = fmaxf(fmaxf(s[i][0], s[i][1]), fmaxf(s[i][2], s[i][3]));
            mn = fmaxf(mn, __shfl_xor(mn, 1));
            mn = fmaxf(mn, __shfl_xor(mn, 2));
            mn = fmaxf(mn, __shfl_xor(mn, 4));
            mn = fmaxf(mn, __shfl_xor(mn, 8));
            float mt = fmaxf(m_i[i], mn);
            float alpha = __expf(m_i[i] - mt);
            m_i[i] = mt;
            float rs = 0.f;
#pragma unroll
            for (int j = 0; j < 4; j++) {
                float e = __expf(s[i][j] - mt);
                s[i][j] = e;
                rs += e;
            }
            rs += __shfl_xor(rs, 1);
            rs += __shfl_xor(rs, 2);
            rs += __shfl_xor(rs, 4);
            rs += __shfl_xor(rs, 8);
            l_i[i] = l_i[i] * alpha + rs;
#pragma unroll
            for (int dd = 0; dd < 4; dd++) o[i][dd] *= alpha;
        }

        // write P tile
#pragma unroll
        for (int i = 0; i < 4; i++)
            *(float4*)&Ps[ty * 4 + i][tx * 4] = make_float4(s[i][0], s[i][1], s[i][2], s[i][3]);
        __syncthreads();

        // O += P V
#pragma unroll 4
        for (int j0 = 0; j0 < BN; j0 += 4) {
            float4 vv0 = *(const float4*)&Vs[j0 + 0][tx * 4];
            float4 vv1 = *(const float4*)&Vs[j0 + 1][tx * 4];
            float4 vv2 = *(const float4*)&Vs[j0 + 2][tx * 4];
            float4 vv3 = *(const float4*)&Vs[j0 + 3][tx * 4];
#pragma unroll
            for (int i = 0; i < 4; i++) {
                float4 pv = *(const float4*)&Ps[ty * 4 + i][j0];
                o[i][0] += pv.x * vv0.x + pv.y * vv1.x + pv.z * vv2.x + pv.w * vv3.x;
                o[i][1] += pv.x * vv0.y + pv.y * vv1.y + pv.z * vv2.y + pv.w * vv3.y;
                o[i][2] += pv.x * vv0.z + pv.y * vv1.z + pv.z * vv2.z + pv.w * vv3.z;
                o[i][3] += pv.x * vv0.w + pv.y * vv1.w + pv.z * vv2.w + pv.w * vv3.w;
            }
        }
    }

    // epilogue: O / l
    float* Ob = Og + ((size_t)b * T) * D_MODEL + h * HEAD_SIZE;
#pragma unroll
    for (int i = 0; i < 4; i++) {
        float inv = 1.f / l_i[i];
        *(float4*)(Ob + (size_t)(q0 + ty * 4 + i) * D_MODEL + tx * 4) =
            make_float4(o[i][0] * inv, o[i][1] * inv, o[i][2] * inv, o[i][3] * inv);
    }
}

extern "C" void kernel_launch(void* const* d_in, const int* in_sizes, int n_in,
                              void* d_out, int out_size, void* d_ws, size_t ws_size,
                              hipStream_t stream) {
    const float* x          = (const float*)d_in[0];
    const float* rms_scale  = (const float*)d_in[1];
    const float* in_proj_w  = (const float*)d_in[2];
    const float* in_proj_b  = (const float*)d_in[3];
    const float* out_proj_w = (const float*)d_in[4];
    const float* out_proj_b = (const float*)d_in[5];
    const float* w1         = (const float*)d_in[6];
    const float* b1         = (const float*)d_in[7];
    const float* w2         = (const float*)d_in[8];
    const float* b2         = (const float*)d_in[9];
    float* out = (float*)d_out;

    const int rows = in_sizes[0] / D_MODEL;  // B*T = 4096
    const int T = SEQ_T;
    const int B = rows / T;
    const size_t R = (size_t)rows * D_MODEL;  // 4M floats

    float* ws = (float*)d_ws;
    float* XN  = ws;            // xn; later CTX; later YN
    float* RP  = ws + R;        // roped xn; later H1 (spans RP..RP+4R)
    float* Qb  = ws + 2 * R;
    float* Kb  = ws + 3 * R;
    float* Vb  = ws + 4 * R;
    float* CTX = XN;
    float* YN  = XN;
    float* H1  = RP;            // rows*4096 floats

    // 1. xn = rmsnorm(x)
    rmsnorm_kernel<<<rows, 256, 0, stream>>>(x, rms_scale, XN);
    // 2. RP = rope(xn)   (q_in == k_in in the reference)
    int total_pairs = rows * NUM_HEADS * (HEAD_SIZE / 2);
    rope_kernel<<<(total_pairs + 255) / 256, 256, 0, stream>>>(XN, RP, total_pairs);
    // 3-5. Q, K, V projections
    {
        dim3 g(D_MODEL / 64, rows / 64);
        gemm_kernel<0, false><<<g, 256, 0, stream>>>(RP, in_proj_w, in_proj_b, Qb,
                                                     rows, D_MODEL, D_MODEL);
        gemm_kernel<0, false><<<g, 256, 0, stream>>>(RP, in_proj_w + (size_t)D_MODEL * D_MODEL,
                                                     in_proj_b + D_MODEL, Kb,
                                                     rows, D_MODEL, D_MODEL);
        gemm_kernel<0, false><<<g, 256, 0, stream>>>(XN, in_proj_w + 2 * (size_t)D_MODEL * D_MODEL,
                                                     in_proj_b + 2 * D_MODEL, Vb,
                                                     rows, D_MODEL, D_MODEL);
    }
    // 6. attention -> CTX
    attn_flash_kernel<<<B * NUM_HEADS * (T / BM), 256, 0, stream>>>(Qb, Kb, Vb, CTX, T);
    // 7. y = CTX @ out_proj_w^T + b  -> d_out
    {
        dim3 g(D_MODEL / 64, rows / 64);
        gemm_kernel<0, false><<<g, 256, 0, stream>>>(CTX, out_proj_w, out_proj_b, out,
                                                     rows, D_MODEL, D_MODEL);
    }
    // 8. yn = rmsnorm(y)
    rmsnorm_kernel<<<rows, 256, 0, stream>>>(out, rms_scale, YN);
    // 9. H1 = silu(yn @ w1^T + b1)
    {
        dim3 g(4 * D_MODEL / 64, rows / 64);
        gemm_kernel<1, false><<<g, 256, 0, stream>>>(YN, w1, b1, H1,
                                                     rows, 4 * D_MODEL, D_MODEL);
    }
    // 10. out += H1 @ w2^T + b2
    {
        dim3 g(D_MODEL / 64, rows / 64);
        gemm_kernel<0, true><<<g, 256, 0, stream>>>(H1, w2, b2, out,
                                                    rows, D_MODEL, 4 * D_MODEL);
    }
}

// Round 3
// 1143.953 us; speedup vs baseline: 6.8003x; 2.5524x over previous
//
#include <hip/hip_runtime.h>
#include <math.h>
#include <stdint.h>

#define D_MODEL 1024
#define NUM_HEADS 16
#define HEAD_SIZE 64
#define SEQ_T 2048

typedef __bf16 bf16;
typedef __bf16 bf16x8 __attribute__((ext_vector_type(8)));
typedef float f32x4 __attribute__((ext_vector_type(4)));

__device__ __forceinline__ void gld_lds16(const bf16* g, bf16* l) {
    __builtin_amdgcn_global_load_lds(
        (__attribute__((address_space(1))) void*)(const_cast<bf16*>(g)),
        (__attribute__((address_space(3))) void*)(l), 16, 0, 0);
}

// ---------------- f32 -> bf16 cast (weights) ----------------
struct __align__(8) b4pack { bf16 v[4]; };
__global__ __launch_bounds__(256) void cast_f32_bf16(const float* __restrict__ src,
                                                     bf16* __restrict__ dst, int n) {
    int i = (blockIdx.x * 256 + threadIdx.x) * 4;
    if (i >= n) return;
    float4 v = *(const float4*)(src + i);
    b4pack o;
    o.v[0] = (bf16)v.x; o.v[1] = (bf16)v.y; o.v[2] = (bf16)v.z; o.v[3] = (bf16)v.w;
    *(b4pack*)(dst + i) = o;
}

// ---------------- RMSNorm: fp32 in, bf16 out ----------------
__global__ __launch_bounds__(256) void rmsnorm_kernel(const float* __restrict__ x,
                                                      const float* __restrict__ scale,
                                                      bf16* __restrict__ out) {
    __shared__ float red[4];
    int row = blockIdx.x;
    const float* xp = x + (size_t)row * D_MODEL;
    bf16* op = out + (size_t)row * D_MODEL;
    int tid = threadIdx.x;
    float s = 0.f;
    for (int i = tid; i < D_MODEL; i += 256) { float v = xp[i]; s += v * v; }
    for (int off = 32; off; off >>= 1) s += __shfl_down(s, off);
    if ((tid & 63) == 0) red[tid >> 6] = s;
    __syncthreads();
    if (tid == 0) red[0] = red[0] + red[1] + red[2] + red[3];
    __syncthreads();
    float inv = rsqrtf(red[0] * (1.0f / D_MODEL) + 1e-6f);
    for (int i = tid; i < D_MODEL; i += 256) op[i] = (bf16)(xp[i] * inv * scale[i]);
}

// ---------------- RoPE: bf16 in/out, interleaved pairs ----------------
__global__ __launch_bounds__(256) void rope_kernel(const bf16* __restrict__ x,
                                                   bf16* __restrict__ out,
                                                   int total_pairs) {
    int p = blockIdx.x * 256 + threadIdx.x;
    if (p >= total_pairs) return;
    int i = p & 31;            // half-dim index
    int rem = p >> 5;          // (b*T + t)*H + h
    int rem2 = rem >> 4;       // b*T + t
    int t = rem2 & (SEQ_T - 1);
    size_t base = (size_t)rem * HEAD_SIZE + 2 * i;
    float theta = expf(-0.2878231366242557f * (float)i);  // ln(10000)/32
    float ang = (float)t * theta;
    float sv, cv;
    sincosf(ang, &sv, &cv);
    float x0 = (float)x[base], x1 = (float)x[base + 1];
    out[base]     = (bf16)(x0 * cv - x1 * sv);
    out[base + 1] = (bf16)(x1 * cv + x0 * sv);
}

// ---------------- bf16 MFMA GEMM (m97 structure) ----------------
// C[M,N] = act(A[M,K] @ W[N,K]^T + bias) (+Cf). 128x128 tile, BK=32,
// 256 thr = 4 waves, each wave 64x64 via 4x4 grid of 16x16x32 MFMA.
// Dual-A: blocks with n0 < splitN read A, else A2 (QKV fusion).
template <int ACT, int ADD, int OUT_BF16>
__global__ __launch_bounds__(256) void gemm_bf16(const bf16* __restrict__ A,
                                                 const bf16* __restrict__ A2, int splitN,
                                                 const bf16* __restrict__ W,
                                                 const float* __restrict__ bias,
                                                 float* __restrict__ Cf,
                                                 bf16* __restrict__ Cb,
                                                 int M, int N, int K) {
    __shared__ __align__(16) bf16 As[128 * 32];
    __shared__ __align__(16) bf16 Bs[128 * 32];
    int tid = threadIdx.x;
    int m0 = blockIdx.y * 128, n0 = blockIdx.x * 128;
    const bf16* Ag = (n0 < splitN) ? A : A2;

    int lane = tid & 63, w = tid >> 6;
    int wm = w >> 1, wn = w & 1;
    int lm = lane & 15, quad = lane >> 4;

    // staging: 512 chunks of 16B per tile; thread t handles chunks t and t+256.
    int c0 = tid, c1 = tid + 256;
    int ar0 = c0 >> 2, ak0 = (c0 & 3) * 8;
    int ar1 = c1 >> 2, ak1 = (c1 & 3) * 8;

    f32x4 acc[4][4];
#pragma unroll
    for (int i = 0; i < 4; i++)
#pragma unroll
        for (int j = 0; j < 4; j++)
#pragma unroll
            for (int r = 0; r < 4; r++) acc[i][j][r] = 0.f;

    int abase = (wm * 64 + lm) * 32 + quad * 8;
    int bbase = (wn * 64 + lm) * 32 + quad * 8;

    for (int k0 = 0; k0 < K; k0 += 32) {
        __syncthreads();  // prev-iter LDS reads complete
        gld_lds16(Ag + (size_t)(m0 + ar0) * K + k0 + ak0, As + c0 * 8);
        gld_lds16(Ag + (size_t)(m0 + ar1) * K + k0 + ak1, As + c1 * 8);
        gld_lds16(W  + (size_t)(n0 + ar0) * K + k0 + ak0, Bs + c0 * 8);
        gld_lds16(W  + (size_t)(n0 + ar1) * K + k0 + ak1, Bs + c1 * 8);
        __syncthreads();  // drains vmcnt -> LDS tiles ready
        bf16x8 af[4], bfr[4];
#pragma unroll
        for (int i = 0; i < 4; i++) af[i] = *(const bf16x8*)&As[abase + i * 16 * 32];
#pragma unroll
        for (int j = 0; j < 4; j++) bfr[j] = *(const bf16x8*)&Bs[bbase + j * 16 * 32];
#pragma unroll
        for (int i = 0; i < 4; i++)
#pragma unroll
            for (int j = 0; j < 4; j++)
                acc[i][j] = __builtin_amdgcn_mfma_f32_16x16x32_bf16(af[i], bfr[j], acc[i][j], 0, 0, 0);
    }

    // epilogue: C/D layout col=lane&15, row=quad*4+reg
#pragma unroll
    for (int j = 0; j < 4; j++) {
        int col = n0 + wn * 64 + j * 16 + lm;
        float bv = bias[col];
#pragma unroll
        for (int i = 0; i < 4; i++) {
#pragma unroll
            for (int r = 0; r < 4; r++) {
                int row = m0 + wm * 64 + i * 16 + quad * 4 + r;
                float v = acc[i][j][r] + bv;
                if (ACT == 1) v = v / (1.f + __expf(-v));  // silu
                size_t idx = (size_t)row * N + col;
                if (ADD) v += Cf[idx];
                if (OUT_BF16) Cb[idx] = (bf16)v;
                else Cf[idx] = v;
            }
        }
    }
}

// ---------------- Flash attention: bf16 QKV (stride 3*D), bf16 out ----------------
__global__ __launch_bounds__(256) void attn_flash_kernel(const bf16* __restrict__ QKV,
                                                         bf16* __restrict__ Og, int T) {
    const int ldq = 3 * D_MODEL;
    __shared__ float Qs[HEAD_SIZE][64];  // [d][i]
    __shared__ float Ks[HEAD_SIZE][64];  // [d][j]
    __shared__ float Vs[64][HEAD_SIZE];  // [j][d]
    __shared__ float Ps[64][64];         // [i][j]

    int nqt = T / 64;  // 32
    int idx = blockIdx.x;
    int qt = (nqt - 1) - (idx % nqt);  // heavy tiles first
    int bh = idx / nqt;
    int h = bh % NUM_HEADS;
    int b = bh / NUM_HEADS;
    int tid = threadIdx.x;
    int tx = tid & 15, ty = tid >> 4;
    int q0 = qt * 64;

    const bf16* Qb = QKV + ((size_t)b * T) * ldq + h * HEAD_SIZE;
    const bf16* Kb = Qb + D_MODEL;
    const bf16* Vb = Qb + 2 * D_MODEL;

    int lr = tid >> 2;          // row 0..63
    int ld0 = (tid & 3) * 16;   // dim base

    // stage Q tile transposed
    {
        const bf16* src = Qb + (size_t)(q0 + lr) * ldq + ld0;
        bf16x8 v0 = *(const bf16x8*)src;
        bf16x8 v1 = *(const bf16x8*)(src + 8);
#pragma unroll
        for (int t = 0; t < 8; t++) {
            Qs[ld0 + t][lr] = (float)v0[t];
            Qs[ld0 + 8 + t][lr] = (float)v1[t];
        }
    }

    float m_i[4], l_i[4], o[4][4];
#pragma unroll
    for (int i = 0; i < 4; i++) {
        m_i[i] = -1e30f;
        l_i[i] = 0.f;
#pragma unroll
        for (int j = 0; j < 4; j++) o[i][j] = 0.f;
    }

    for (int kt = 0; kt <= qt; kt++) {
        int k0 = kt * 64;
        __syncthreads();
        {
            const bf16* ksrc = Kb + (size_t)(k0 + lr) * ldq + ld0;
            const bf16* vsrc = Vb + (size_t)(k0 + lr) * ldq + ld0;
            bf16x8 k0v = *(const bf16x8*)ksrc;
            bf16x8 k1v = *(const bf16x8*)(ksrc + 8);
            bf16x8 v0v = *(const bf16x8*)vsrc;
            bf16x8 v1v = *(const bf16x8*)(vsrc + 8);
#pragma unroll
            for (int t = 0; t < 8; t++) {
                Ks[ld0 + t][lr] = (float)k0v[t];
                Ks[ld0 + 8 + t][lr] = (float)k1v[t];
                Vs[lr][ld0 + t] = (float)v0v[t];
                Vs[lr][ld0 + 8 + t] = (float)v1v[t];
            }
        }
        __syncthreads();

        float s[4][4] = {};
#pragma unroll 8
        for (int d = 0; d < HEAD_SIZE; d++) {
            float4 qv = *(const float4*)&Qs[d][ty * 4];
            float4 kv = *(const float4*)&Ks[d][tx * 4];
            float qa[4] = {qv.x, qv.y, qv.z, qv.w};
            float ka[4] = {kv.x, kv.y, kv.z, kv.w};
#pragma unroll
            for (int i = 0; i < 4; i++)
#pragma unroll
                for (int j = 0; j < 4; j++) s[i][j] += qa[i] * ka[j];
        }
        bool diag = (kt == qt);
#pragma unroll
        for (int i = 0; i < 4; i++)
#pragma unroll
            for (int j = 0; j < 4; j++) {
                float v = s[i][j] * 0.125f;
                if (diag && (tx * 4 + j > ty * 4 + i)) v = -1e30f;
                s[i][j] = v;
            }

#pragma unroll
        for (int i = 0; i < 4; i++) {
            float mn = fmaxf(fmaxf(s[i][0], s[i][1]), fmaxf(s[i][2], s[i][3]));
            mn = fmaxf(mn, __shfl_xor(mn, 1));
            mn = fmaxf(mn, __shfl_xor(mn, 2));
            mn = fmaxf(mn, __shfl_xor(mn, 4));
            mn = fmaxf(mn, __shfl_xor(mn, 8));
            float mt = fmaxf(m_i[i], mn);
            float alpha = __expf(m_i[i] - mt);
            m_i[i] = mt;
            float rs = 0.f;
#pragma unroll
            for (int j = 0; j < 4; j++) {
                float e = __expf(s[i][j] - mt);
                s[i][j] = e;
                rs += e;
            }
            rs += __shfl_xor(rs, 1);
            rs += __shfl_xor(rs, 2);
            rs += __shfl_xor(rs, 4);
            rs += __shfl_xor(rs, 8);
            l_i[i] = l_i[i] * alpha + rs;
#pragma unroll
            for (int dd = 0; dd < 4; dd++) o[i][dd] *= alpha;
        }

#pragma unroll
        for (int i = 0; i < 4; i++)
            *(float4*)&Ps[ty * 4 + i][tx * 4] = make_float4(s[i][0], s[i][1], s[i][2], s[i][3]);
        __syncthreads();

#pragma unroll 4
        for (int j0 = 0; j0 < 64; j0 += 4) {
            float4 vv0 = *(const float4*)&Vs[j0 + 0][tx * 4];
            float4 vv1 = *(const float4*)&Vs[j0 + 1][tx * 4];
            float4 vv2 = *(const float4*)&Vs[j0 + 2][tx * 4];
            float4 vv3 = *(const float4*)&Vs[j0 + 3][tx * 4];
#pragma unroll
            for (int i = 0; i < 4; i++) {
                float4 pv = *(const float4*)&Ps[ty * 4 + i][j0];
                o[i][0] += pv.x * vv0.x + pv.y * vv1.x + pv.z * vv2.x + pv.w * vv3.x;
                o[i][1] += pv.x * vv0.y + pv.y * vv1.y + pv.z * vv2.y + pv.w * vv3.y;
                o[i][2] += pv.x * vv0.z + pv.y * vv1.z + pv.z * vv2.z + pv.w * vv3.z;
                o[i][3] += pv.x * vv0.w + pv.y * vv1.w + pv.z * vv2.w + pv.w * vv3.w;
            }
        }
    }

    bf16* Ob = Og + ((size_t)b * T) * D_MODEL + h * HEAD_SIZE;
#pragma unroll
    for (int i = 0; i < 4; i++) {
        float inv = 1.f / l_i[i];
        b4pack pk;
        pk.v[0] = (bf16)(o[i][0] * inv);
        pk.v[1] = (bf16)(o[i][1] * inv);
        pk.v[2] = (bf16)(o[i][2] * inv);
        pk.v[3] = (bf16)(o[i][3] * inv);
        *(b4pack*)(Ob + (size_t)(q0 + ty * 4 + i) * D_MODEL + tx * 4) = pk;
    }
}

extern "C" void kernel_launch(void* const* d_in, const int* in_sizes, int n_in,
                              void* d_out, int out_size, void* d_ws, size_t ws_size,
                              hipStream_t stream) {
    const float* x          = (const float*)d_in[0];
    const float* rms_scale  = (const float*)d_in[1];
    const float* in_proj_w  = (const float*)d_in[2];
    const float* in_proj_b  = (const float*)d_in[3];
    const float* out_proj_w = (const float*)d_in[4];
    const float* out_proj_b = (const float*)d_in[5];
    const float* w1         = (const float*)d_in[6];
    const float* b1         = (const float*)d_in[7];
    const float* w2         = (const float*)d_in[8];
    const float* b2         = (const float*)d_in[9];
    float* out = (float*)d_out;

    const int rows = in_sizes[0] / D_MODEL;  // 4096
    const int T = SEQ_T;
    const int B = rows / T;
    const int D = D_MODEL;

    // workspace layout (72 MB)
    bf16* inwb  = (bf16*)d_ws;                       // 3M
    bf16* outwb = inwb + (size_t)3 * D * D;          // 1M
    bf16* w1b   = outwb + (size_t)D * D;             // 4M
    bf16* w2b   = w1b + (size_t)4 * D * D;           // 4M
    bf16* XNb   = w2b + (size_t)4 * D * D;           // rows*D (reused as CTXb)
    bf16* RPb   = XNb + (size_t)rows * D;            // rows*D (reused as YNb)
    bf16* QKV   = RPb + (size_t)rows * D;            // rows*3D (reused as H1b rows*4D)
    bf16* CTXb  = XNb;
    bf16* YNb   = RPb;
    bf16* H1b   = QKV;

    // 0. cast weights to bf16
    {
        int n;
        n = 3 * D * D; cast_f32_bf16<<<(n / 4 + 255) / 256, 256, 0, stream>>>(in_proj_w, inwb, n);
        n = D * D;     cast_f32_bf16<<<(n / 4 + 255) / 256, 256, 0, stream>>>(out_proj_w, outwb, n);
        n = 4 * D * D; cast_f32_bf16<<<(n / 4 + 255) / 256, 256, 0, stream>>>(w1, w1b, n);
        n = 4 * D * D; cast_f32_bf16<<<(n / 4 + 255) / 256, 256, 0, stream>>>(w2, w2b, n);
    }
    // 1. xn = rmsnorm(x) -> bf16
    rmsnorm_kernel<<<rows, 256, 0, stream>>>(x, rms_scale, XNb);
    // 2. RPb = rope(xn)
    int total_pairs = rows * NUM_HEADS * (HEAD_SIZE / 2);
    rope_kernel<<<(total_pairs + 255) / 256, 256, 0, stream>>>(XNb, RPb, total_pairs);
    // 3. fused QKV projection: [M,3072]; Q/K read RPb, V reads XNb
    {
        dim3 g(3 * D / 128, rows / 128);
        gemm_bf16<0, 0, 1><<<g, 256, 0, stream>>>(RPb, XNb, 2 * D, inwb, in_proj_b,
                                                  nullptr, QKV, rows, 3 * D, D);
    }
    // 4. attention -> CTXb (bf16)
    attn_flash_kernel<<<B * NUM_HEADS * (T / 64), 256, 0, stream>>>(QKV, CTXb, T);
    // 5. y = CTXb @ out_proj^T + b -> d_out (fp32)
    {
        dim3 g(D / 128, rows / 128);
        gemm_bf16<0, 0, 0><<<g, 256, 0, stream>>>(CTXb, CTXb, D, outwb, out_proj_b,
                                                  out, nullptr, rows, D, D);
    }
    // 6. yn = rmsnorm(y) -> bf16
    rmsnorm_kernel<<<rows, 256, 0, stream>>>(out, rms_scale, YNb);
    // 7. H1b = silu(yn @ w1^T + b1) (bf16)
    {
        dim3 g(4 * D / 128, rows / 128);
        gemm_bf16<1, 0, 1><<<g, 256, 0, stream>>>(YNb, YNb, 4 * D, w1b, b1,
                                                  nullptr, H1b, rows, 4 * D, D);
    }
    // 8. out += H1b @ w2^T + b2 (fp32 residual)
    {
        dim3 g(D / 128, rows / 128);
        gemm_bf16<0, 1, 0><<<g, 256, 0, stream>>>(H1b, H1b, D, w2b, b2,
                                                  out, nullptr, rows, D, 4 * D);
    }
}

// Round 4
// 604.928 us; speedup vs baseline: 12.8598x; 1.8911x over previous
//
#include <hip/hip_runtime.h>
#include <math.h>
#include <stdint.h>

#define D_MODEL 1024
#define NUM_HEADS 16
#define HEAD_SIZE 64
#define SEQ_T 2048

typedef __bf16 bf16;
typedef __bf16 bf16x8 __attribute__((ext_vector_type(8)));
typedef float f32x4 __attribute__((ext_vector_type(4)));

__device__ __forceinline__ void gld_lds16(const bf16* g, bf16* l) {
    __builtin_amdgcn_global_load_lds(
        (__attribute__((address_space(1))) void*)(const_cast<bf16*>(g)),
        (__attribute__((address_space(3))) void*)(l), 16, 0, 0);
}

struct __align__(8) b4pack { bf16 v[4]; };

// ---------------- f32 -> bf16 cast (weights) ----------------
__global__ __launch_bounds__(256) void cast_f32_bf16(const float* __restrict__ src,
                                                     bf16* __restrict__ dst, int n) {
    int i = (blockIdx.x * 256 + threadIdx.x) * 4;
    if (i >= n) return;
    float4 v = *(const float4*)(src + i);
    b4pack o;
    o.v[0] = (bf16)v.x; o.v[1] = (bf16)v.y; o.v[2] = (bf16)v.z; o.v[3] = (bf16)v.w;
    *(b4pack*)(dst + i) = o;
}

// ---------------- RMSNorm: fp32 in, bf16 out ----------------
__global__ __launch_bounds__(256) void rmsnorm_kernel(const float* __restrict__ x,
                                                      const float* __restrict__ scale,
                                                      bf16* __restrict__ out) {
    __shared__ float red[4];
    int row = blockIdx.x;
    const float* xp = x + (size_t)row * D_MODEL;
    bf16* op = out + (size_t)row * D_MODEL;
    int tid = threadIdx.x;
    float s = 0.f;
    for (int i = tid; i < D_MODEL; i += 256) { float v = xp[i]; s += v * v; }
    for (int off = 32; off; off >>= 1) s += __shfl_down(s, off);
    if ((tid & 63) == 0) red[tid >> 6] = s;
    __syncthreads();
    if (tid == 0) red[0] = red[0] + red[1] + red[2] + red[3];
    __syncthreads();
    float inv = rsqrtf(red[0] * (1.0f / D_MODEL) + 1e-6f);
    for (int i = tid; i < D_MODEL; i += 256) op[i] = (bf16)(xp[i] * inv * scale[i]);
}

// ---------------- RoPE: bf16 in/out, interleaved pairs ----------------
__global__ __launch_bounds__(256) void rope_kernel(const bf16* __restrict__ x,
                                                   bf16* __restrict__ out,
                                                   int total_pairs) {
    int p = blockIdx.x * 256 + threadIdx.x;
    if (p >= total_pairs) return;
    int i = p & 31;
    int rem = p >> 5;
    int rem2 = rem >> 4;
    int t = rem2 & (SEQ_T - 1);
    size_t base = (size_t)rem * HEAD_SIZE + 2 * i;
    float theta = expf(-0.2878231366242557f * (float)i);  // ln(10000)/32
    float ang = (float)t * theta;
    float sv, cv;
    sincosf(ang, &sv, &cv);
    float x0 = (float)x[base], x1 = (float)x[base + 1];
    out[base]     = (bf16)(x0 * cv - x1 * sv);
    out[base + 1] = (bf16)(x1 * cv + x0 * sv);
}

// ---------------- bf16 MFMA GEMM (m97 structure) ----------------
// C[M,N] = act(A[M,K] @ W[N,K]^T + bias) (+Cf). Dual-A via splitN.
// VT mode: blocks with n0 >= 2048 write output transposed to Vtp[b][dim][t].
template <int ACT, int ADD, int OUT_BF16, int VT>
__global__ __launch_bounds__(256) void gemm_bf16(const bf16* __restrict__ A,
                                                 const bf16* __restrict__ A2, int splitN,
                                                 const bf16* __restrict__ W,
                                                 const float* __restrict__ bias,
                                                 float* __restrict__ Cf,
                                                 bf16* __restrict__ Cb,
                                                 bf16* __restrict__ Vtp, int Tlen,
                                                 int M, int N, int K) {
    __shared__ __align__(16) bf16 As[128 * 32];
    __shared__ __align__(16) bf16 Bs[128 * 32];
    int tid = threadIdx.x;
    int m0 = blockIdx.y * 128, n0 = blockIdx.x * 128;
    const bf16* Ag = (n0 < splitN) ? A : A2;

    int lane = tid & 63, w = tid >> 6;
    int wm = w >> 1, wn = w & 1;
    int lm = lane & 15, quad = lane >> 4;

    int c0 = tid, c1 = tid + 256;
    int ar0 = c0 >> 2, ak0 = (c0 & 3) * 8;
    int ar1 = c1 >> 2, ak1 = (c1 & 3) * 8;

    f32x4 acc[4][4];
#pragma unroll
    for (int i = 0; i < 4; i++)
#pragma unroll
        for (int j = 0; j < 4; j++)
#pragma unroll
            for (int r = 0; r < 4; r++) acc[i][j][r] = 0.f;

    int abase = (wm * 64 + lm) * 32 + quad * 8;
    int bbase = (wn * 64 + lm) * 32 + quad * 8;

    for (int k0 = 0; k0 < K; k0 += 32) {
        __syncthreads();
        gld_lds16(Ag + (size_t)(m0 + ar0) * K + k0 + ak0, As + c0 * 8);
        gld_lds16(Ag + (size_t)(m0 + ar1) * K + k0 + ak1, As + c1 * 8);
        gld_lds16(W  + (size_t)(n0 + ar0) * K + k0 + ak0, Bs + c0 * 8);
        gld_lds16(W  + (size_t)(n0 + ar1) * K + k0 + ak1, Bs + c1 * 8);
        __syncthreads();
        bf16x8 af[4], bfr[4];
#pragma unroll
        for (int i = 0; i < 4; i++) af[i] = *(const bf16x8*)&As[abase + i * 16 * 32];
#pragma unroll
        for (int j = 0; j < 4; j++) bfr[j] = *(const bf16x8*)&Bs[bbase + j * 16 * 32];
#pragma unroll
        for (int i = 0; i < 4; i++)
#pragma unroll
            for (int j = 0; j < 4; j++)
                acc[i][j] = __builtin_amdgcn_mfma_f32_16x16x32_bf16(af[i], bfr[j], acc[i][j], 0, 0, 0);
    }

    if (VT && n0 >= 2 * D_MODEL) {
        // transposed V store: Vtp[b][dim][token], packed over r (4 consecutive tokens)
#pragma unroll
        for (int j = 0; j < 4; j++) {
            int col = n0 + wn * 64 + j * 16 + lm;
            int dimg = col - 2 * D_MODEL;
            float bv = bias[col];
#pragma unroll
            for (int i = 0; i < 4; i++) {
                int row0 = m0 + wm * 64 + i * 16 + quad * 4;
                int bb = row0 / Tlen, t0 = row0 % Tlen;
                b4pack pk;
#pragma unroll
                for (int r = 0; r < 4; r++) pk.v[r] = (bf16)(acc[i][j][r] + bv);
                *(b4pack*)(Vtp + ((size_t)bb * D_MODEL + dimg) * Tlen + t0) = pk;
            }
        }
        return;
    }

#pragma unroll
    for (int j = 0; j < 4; j++) {
        int col = n0 + wn * 64 + j * 16 + lm;
        float bv = bias[col];
#pragma unroll
        for (int i = 0; i < 4; i++) {
#pragma unroll
            for (int r = 0; r < 4; r++) {
                int row = m0 + wm * 64 + i * 16 + quad * 4 + r;
                float v = acc[i][j][r] + bv;
                if (ACT == 1) v = v / (1.f + __expf(-v));
                size_t idx = (size_t)row * N + col;
                if (ADD) v += Cf[idx];
                if (OUT_BF16) Cb[idx] = (bf16)v;
                else Cf[idx] = v;
            }
        }
    }
}

// ---------------- MFMA flash attention, barrier-free ----------------
// One block = 4 waves; wave w owns 16 q-rows. Q frags in registers; K/V frags
// read directly from global (L2). P round-trips through per-wave XOR-swizzled
// LDS (C/D layout -> A layout, per m120). No __syncthreads.
__global__ __launch_bounds__(256) void attn_mfma_kernel(const bf16* __restrict__ QKV,
                                                        const bf16* __restrict__ Vt,
                                                        bf16* __restrict__ Og, int T) {
    __shared__ __align__(16) bf16 Ps[4 * 16 * 64];  // 8 KB, 128B rows, XOR-swizzled
    const int ldq = 3 * D_MODEL;
    const int nqt = T / 64;
    int idx = blockIdx.x;
    int qt = (nqt - 1) - (idx % nqt);  // heavy tiles first
    int bh = idx / nqt;
    int h = bh & (NUM_HEADS - 1), b = bh / NUM_HEADS;
    int tid = threadIdx.x;
    int w = tid >> 6, lane = tid & 63;
    int lm = lane & 15, quad = lane >> 4;
    int q0 = qt * 64, qrow0 = q0 + w * 16;

    // Q fragments (A-layout: m=lm, k=quad*8+j (+32))
    const bf16* Qp = QKV + ((size_t)(b * T + qrow0 + lm)) * ldq + h * HEAD_SIZE + quad * 8;
    bf16x8 qf0 = *(const bf16x8*)Qp;
    bf16x8 qf1 = *(const bf16x8*)(Qp + 32);

    const bf16* Kbase = QKV + ((size_t)b * T) * ldq + D_MODEL + h * HEAD_SIZE;
    const bf16* Vbase = Vt + ((size_t)b * D_MODEL + h * HEAD_SIZE) * T;

    f32x4 o[4];
    float m_i[4], l_i[4];
#pragma unroll
    for (int r = 0; r < 4; r++) {
        m_i[r] = -3.0e38f;
        l_i[r] = 0.f;
        o[r] = (f32x4){0.f, 0.f, 0.f, 0.f};
    }

    const float C = 0.1803368801111204f;  // 0.125 * log2(e)
    bf16* PsW = Ps + w * 16 * 64;
    int lm7 = lm & 7;

    for (int kt = 0; kt <= qt; kt++) {
        int k0 = kt * 64;
        // ---- S = Q K^T (raw, scale folded into exp) ----
        f32x4 s[4];
#pragma unroll
        for (int jb = 0; jb < 4; jb++) {
            const bf16* kp = Kbase + (size_t)(k0 + jb * 16 + lm) * ldq + quad * 8;
            bf16x8 kf0 = *(const bf16x8*)kp;
            bf16x8 kf1 = *(const bf16x8*)(kp + 32);
            f32x4 a = {0.f, 0.f, 0.f, 0.f};
            a = __builtin_amdgcn_mfma_f32_16x16x32_bf16(qf0, kf0, a, 0, 0, 0);
            a = __builtin_amdgcn_mfma_f32_16x16x32_bf16(qf1, kf1, a, 0, 0, 0);
            s[jb] = a;
        }
        // ---- causal mask (only the diagonal k-tile can violate) ----
        if (kt == qt) {
#pragma unroll
            for (int jb = 0; jb < 4; jb++)
#pragma unroll
                for (int r = 0; r < 4; r++)
                    if (k0 + jb * 16 + lm > qrow0 + quad * 4 + r) s[jb][r] = -3.0e38f;
        }
        // ---- online softmax (rows = quad*4+r; 16 row-mates share quad) ----
#pragma unroll
        for (int r = 0; r < 4; r++) {
            float mn = fmaxf(fmaxf(s[0][r], s[1][r]), fmaxf(s[2][r], s[3][r]));
            mn = fmaxf(mn, __shfl_xor(mn, 1));
            mn = fmaxf(mn, __shfl_xor(mn, 2));
            mn = fmaxf(mn, __shfl_xor(mn, 4));
            mn = fmaxf(mn, __shfl_xor(mn, 8));
            float mt = fmaxf(m_i[r], mn);
            float alpha = exp2f((m_i[r] - mt) * C);
            m_i[r] = mt;
            float nb = -mt * C;
            float rs = 0.f;
#pragma unroll
            for (int jb = 0; jb < 4; jb++) {
                float p = exp2f(fmaf(s[jb][r], C, nb));
                s[jb][r] = p;
                rs += p;
            }
            rs += __shfl_xor(rs, 1);
            rs += __shfl_xor(rs, 2);
            rs += __shfl_xor(rs, 4);
            rs += __shfl_xor(rs, 8);
            l_i[r] = l_i[r] * alpha + rs;
#pragma unroll
            for (int db = 0; db < 4; db++) o[db][r] *= alpha;
        }
        // ---- P: C/D layout -> LDS (XOR swizzle: slot = keygroup ^ (row&7)) ----
#pragma unroll
        for (int jb = 0; jb < 4; jb++) {
            int g = jb * 2 + (lm >> 3);
#pragma unroll
            for (int r = 0; r < 4; r++) {
                int row = quad * 4 + r;
                PsW[row * 64 + ((g ^ (row & 7)) * 8) + lm7] = (bf16)s[jb][r];
            }
        }
        // ---- O += P V  (A = P from LDS, B = V^T frags from global) ----
        bf16x8 pf0 = *(const bf16x8*)&PsW[lm * 64 + ((quad ^ lm7) * 8)];
        bf16x8 pf1 = *(const bf16x8*)&PsW[lm * 64 + (((quad + 4) ^ lm7) * 8)];
#pragma unroll
        for (int db = 0; db < 4; db++) {
            const bf16* vp = Vbase + (size_t)(db * 16 + lm) * T + k0 + quad * 8;
            bf16x8 vf0 = *(const bf16x8*)vp;
            bf16x8 vf1 = *(const bf16x8*)(vp + 32);
            o[db] = __builtin_amdgcn_mfma_f32_16x16x32_bf16(pf0, vf0, o[db], 0, 0, 0);
            o[db] = __builtin_amdgcn_mfma_f32_16x16x32_bf16(pf1, vf1, o[db], 0, 0, 0);
        }
    }

    // ---- epilogue: O / l -> bf16 ----
    float inv[4];
#pragma unroll
    for (int r = 0; r < 4; r++) inv[r] = 1.f / l_i[r];
    bf16* Ob = Og + ((size_t)(b * T + qrow0 + quad * 4)) * D_MODEL + h * HEAD_SIZE + lm;
#pragma unroll
    for (int r = 0; r < 4; r++)
#pragma unroll
        for (int db = 0; db < 4; db++)
            Ob[(size_t)r * D_MODEL + db * 16] = (bf16)(o[db][r] * inv[r]);
}

extern "C" void kernel_launch(void* const* d_in, const int* in_sizes, int n_in,
                              void* d_out, int out_size, void* d_ws, size_t ws_size,
                              hipStream_t stream) {
    const float* x          = (const float*)d_in[0];
    const float* rms_scale  = (const float*)d_in[1];
    const float* in_proj_w  = (const float*)d_in[2];
    const float* in_proj_b  = (const float*)d_in[3];
    const float* out_proj_w = (const float*)d_in[4];
    const float* out_proj_b = (const float*)d_in[5];
    const float* w1         = (const float*)d_in[6];
    const float* b1         = (const float*)d_in[7];
    const float* w2         = (const float*)d_in[8];
    const float* b2         = (const float*)d_in[9];
    float* out = (float*)d_out;

    const int rows = in_sizes[0] / D_MODEL;  // 4096
    const int T = SEQ_T;
    const int B = rows / T;
    const int D = D_MODEL;

    // workspace layout (same footprint as R3; Vt lives in the H1 tail)
    bf16* inwb  = (bf16*)d_ws;                       // 3M
    bf16* outwb = inwb + (size_t)3 * D * D;          // 1M
    bf16* w1b   = outwb + (size_t)D * D;             // 4M
    bf16* w2b   = w1b + (size_t)4 * D * D;           // 4M
    bf16* XNb   = w2b + (size_t)4 * D * D;           // rows*D (reused as CTXb)
    bf16* RPb   = XNb + (size_t)rows * D;            // rows*D (reused as YNb)
    bf16* QKV   = RPb + (size_t)rows * D;            // rows*3D (H1b spans rows*4D)
    bf16* Vt    = QKV + (size_t)rows * 3 * D;        // rows*D  (tail of H1b region)
    bf16* CTXb  = XNb;
    bf16* YNb   = RPb;
    bf16* H1b   = QKV;

    // 0. cast weights to bf16
    {
        int n;
        n = 3 * D * D; cast_f32_bf16<<<(n / 4 + 255) / 256, 256, 0, stream>>>(in_proj_w, inwb, n);
        n = D * D;     cast_f32_bf16<<<(n / 4 + 255) / 256, 256, 0, stream>>>(out_proj_w, outwb, n);
        n = 4 * D * D; cast_f32_bf16<<<(n / 4 + 255) / 256, 256, 0, stream>>>(w1, w1b, n);
        n = 4 * D * D; cast_f32_bf16<<<(n / 4 + 255) / 256, 256, 0, stream>>>(w2, w2b, n);
    }
    // 1. xn = rmsnorm(x) -> bf16
    rmsnorm_kernel<<<rows, 256, 0, stream>>>(x, rms_scale, XNb);
    // 2. RPb = rope(xn)
    int total_pairs = rows * NUM_HEADS * (HEAD_SIZE / 2);
    rope_kernel<<<(total_pairs + 255) / 256, 256, 0, stream>>>(XNb, RPb, total_pairs);
    // 3. fused QKV projection; Q/K -> QKV buffer, V -> Vt (transposed)
    {
        dim3 g(3 * D / 128, rows / 128);
        gemm_bf16<0, 0, 1, 1><<<g, 256, 0, stream>>>(RPb, XNb, 2 * D, inwb, in_proj_b,
                                                     nullptr, QKV, Vt, T, rows, 3 * D, D);
    }
    // 4. attention -> CTXb (bf16)
    attn_mfma_kernel<<<B * NUM_HEADS * (T / 64), 256, 0, stream>>>(QKV, Vt, CTXb, T);
    // 5. y = CTXb @ out_proj^T + b -> d_out (fp32)
    {
        dim3 g(D / 128, rows / 128);
        gemm_bf16<0, 0, 0, 0><<<g, 256, 0, stream>>>(CTXb, CTXb, D, outwb, out_proj_b,
                                                     out, nullptr, nullptr, 1, rows, D, D);
    }
    // 6. yn = rmsnorm(y) -> bf16
    rmsnorm_kernel<<<rows, 256, 0, stream>>>(out, rms_scale, YNb);
    // 7. H1b = silu(yn @ w1^T + b1) (bf16)
    {
        dim3 g(4 * D / 128, rows / 128);
        gemm_bf16<1, 0, 1, 0><<<g, 256, 0, stream>>>(YNb, YNb, 4 * D, w1b, b1,
                                                     nullptr, H1b, nullptr, 1, rows, 4 * D, D);
    }
    // 8. out += H1b @ w2^T + b2 (fp32 residual)
    {
        dim3 g(D / 128, rows / 128);
        gemm_bf16<0, 1, 0, 0><<<g, 256, 0, stream>>>(H1b, H1b, D, w2b, b2,
                                                     out, nullptr, nullptr, 1, rows, D, 4 * D);
    }
}

// Round 5
// 543.060 us; speedup vs baseline: 14.3248x; 1.1139x over previous
//
#include <hip/hip_runtime.h>
#include <math.h>
#include <stdint.h>

#define D_MODEL 1024
#define NUM_HEADS 16
#define HEAD_SIZE 64
#define SEQ_T 2048

typedef __bf16 bf16;
typedef __bf16 bf16x8 __attribute__((ext_vector_type(8)));
typedef float f32x4 __attribute__((ext_vector_type(4)));

__device__ __forceinline__ void gld_lds16(const bf16* g, bf16* l) {
    __builtin_amdgcn_global_load_lds(
        (__attribute__((address_space(1))) void*)(const_cast<bf16*>(g)),
        (__attribute__((address_space(3))) void*)(l), 16, 0, 0);
}

struct __align__(8) b4pack { bf16 v[4]; };

// ---------------- f32 -> bf16 cast (weights) ----------------
__global__ __launch_bounds__(256) void cast_f32_bf16(const float* __restrict__ src,
                                                     bf16* __restrict__ dst, int n) {
    int i = (blockIdx.x * 256 + threadIdx.x) * 4;
    if (i >= n) return;
    float4 v = *(const float4*)(src + i);
    b4pack o;
    o.v[0] = (bf16)v.x; o.v[1] = (bf16)v.y; o.v[2] = (bf16)v.z; o.v[3] = (bf16)v.w;
    *(b4pack*)(dst + i) = o;
}

// ---------------- fused RMSNorm + RoPE: fp32 in, bf16 xn + bf16 roped out ----------------
// One block per token row; thread handles 4 dims = 2 interleaved pairs.
__global__ __launch_bounds__(256) void rmsnorm_rope_kernel(const float* __restrict__ x,
                                                           const float* __restrict__ scale,
                                                           bf16* __restrict__ xn,
                                                           bf16* __restrict__ rp, int T) {
    __shared__ float red[4];
    int row = blockIdx.x;
    int t = row % T;
    const float* xp = x + (size_t)row * D_MODEL;
    int tid = threadIdx.x;
    float4 xv = *(const float4*)(xp + tid * 4);
    float s = xv.x * xv.x + xv.y * xv.y + xv.z * xv.z + xv.w * xv.w;
    for (int off = 32; off; off >>= 1) s += __shfl_down(s, off);
    if ((tid & 63) == 0) red[tid >> 6] = s;
    __syncthreads();
    if (tid == 0) red[0] = red[0] + red[1] + red[2] + red[3];
    __syncthreads();
    float inv = rsqrtf(red[0] * (1.0f / D_MODEL) + 1e-6f);
    float4 sc = *(const float4*)(scale + tid * 4);
    float n0 = xv.x * inv * sc.x, n1 = xv.y * inv * sc.y;
    float n2 = xv.z * inv * sc.z, n3 = xv.w * inv * sc.w;
    b4pack pn;
    pn.v[0] = (bf16)n0; pn.v[1] = (bf16)n1; pn.v[2] = (bf16)n2; pn.v[3] = (bf16)n3;
    *(b4pack*)(xn + (size_t)row * D_MODEL + tid * 4) = pn;
    // rope: pairs p0=2*tid, p1=2*tid+1; within-head pair idx = p & 31
    int p0 = 2 * tid;
    float th0 = expf(-0.2878231366242557f * (float)(p0 & 31));        // ln(10000)/32
    float th1 = expf(-0.2878231366242557f * (float)((p0 + 1) & 31));
    float s0, c0, s1, c1;
    sincosf((float)t * th0, &s0, &c0);
    sincosf((float)t * th1, &s1, &c1);
    b4pack pr;
    pr.v[0] = (bf16)(n0 * c0 - n1 * s0);
    pr.v[1] = (bf16)(n1 * c0 + n0 * s0);
    pr.v[2] = (bf16)(n2 * c1 - n3 * s1);
    pr.v[3] = (bf16)(n3 * c1 + n2 * s1);
    *(b4pack*)(rp + (size_t)row * D_MODEL + tid * 4) = pr;
}

// ---------------- RMSNorm only: fp32 in, bf16 out ----------------
__global__ __launch_bounds__(256) void rmsnorm_kernel(const float* __restrict__ x,
                                                      const float* __restrict__ scale,
                                                      bf16* __restrict__ out) {
    __shared__ float red[4];
    int row = blockIdx.x;
    const float* xp = x + (size_t)row * D_MODEL;
    bf16* op = out + (size_t)row * D_MODEL;
    int tid = threadIdx.x;
    float s = 0.f;
    for (int i = tid; i < D_MODEL; i += 256) { float v = xp[i]; s += v * v; }
    for (int off = 32; off; off >>= 1) s += __shfl_down(s, off);
    if ((tid & 63) == 0) red[tid >> 6] = s;
    __syncthreads();
    if (tid == 0) red[0] = red[0] + red[1] + red[2] + red[3];
    __syncthreads();
    float inv = rsqrtf(red[0] * (1.0f / D_MODEL) + 1e-6f);
    for (int i = tid; i < D_MODEL; i += 256) op[i] = (bf16)(xp[i] * inv * scale[i]);
}

// ---------------- bf16 MFMA GEMM (m97 structure) ----------------
template <int ACT, int ADD, int OUT_BF16, int VT>
__global__ __launch_bounds__(256) void gemm_bf16(const bf16* __restrict__ A,
                                                 const bf16* __restrict__ A2, int splitN,
                                                 const bf16* __restrict__ W,
                                                 const float* __restrict__ bias,
                                                 float* __restrict__ Cf,
                                                 bf16* __restrict__ Cb,
                                                 bf16* __restrict__ Vtp, int Tlen,
                                                 int M, int N, int K) {
    __shared__ __align__(16) bf16 As[128 * 32];
    __shared__ __align__(16) bf16 Bs[128 * 32];
    int tid = threadIdx.x;
    int m0 = blockIdx.y * 128, n0 = blockIdx.x * 128;
    const bf16* Ag = (n0 < splitN) ? A : A2;

    int lane = tid & 63, w = tid >> 6;
    int wm = w >> 1, wn = w & 1;
    int lm = lane & 15, quad = lane >> 4;

    int c0 = tid, c1 = tid + 256;
    int ar0 = c0 >> 2, ak0 = (c0 & 3) * 8;
    int ar1 = c1 >> 2, ak1 = (c1 & 3) * 8;

    f32x4 acc[4][4];
#pragma unroll
    for (int i = 0; i < 4; i++)
#pragma unroll
        for (int j = 0; j < 4; j++)
#pragma unroll
            for (int r = 0; r < 4; r++) acc[i][j][r] = 0.f;

    int abase = (wm * 64 + lm) * 32 + quad * 8;
    int bbase = (wn * 64 + lm) * 32 + quad * 8;

    for (int k0 = 0; k0 < K; k0 += 32) {
        __syncthreads();
        gld_lds16(Ag + (size_t)(m0 + ar0) * K + k0 + ak0, As + c0 * 8);
        gld_lds16(Ag + (size_t)(m0 + ar1) * K + k0 + ak1, As + c1 * 8);
        gld_lds16(W  + (size_t)(n0 + ar0) * K + k0 + ak0, Bs + c0 * 8);
        gld_lds16(W  + (size_t)(n0 + ar1) * K + k0 + ak1, Bs + c1 * 8);
        __syncthreads();
        bf16x8 af[4], bfr[4];
#pragma unroll
        for (int i = 0; i < 4; i++) af[i] = *(const bf16x8*)&As[abase + i * 16 * 32];
#pragma unroll
        for (int j = 0; j < 4; j++) bfr[j] = *(const bf16x8*)&Bs[bbase + j * 16 * 32];
#pragma unroll
        for (int i = 0; i < 4; i++)
#pragma unroll
            for (int j = 0; j < 4; j++)
                acc[i][j] = __builtin_amdgcn_mfma_f32_16x16x32_bf16(af[i], bfr[j], acc[i][j], 0, 0, 0);
    }

    if (VT && n0 >= 2 * D_MODEL) {
#pragma unroll
        for (int j = 0; j < 4; j++) {
            int col = n0 + wn * 64 + j * 16 + lm;
            int dimg = col - 2 * D_MODEL;
            float bv = bias[col];
#pragma unroll
            for (int i = 0; i < 4; i++) {
                int row0 = m0 + wm * 64 + i * 16 + quad * 4;
                int bb = row0 / Tlen, t0 = row0 % Tlen;
                b4pack pk;
#pragma unroll
                for (int r = 0; r < 4; r++) pk.v[r] = (bf16)(acc[i][j][r] + bv);
                *(b4pack*)(Vtp + ((size_t)bb * D_MODEL + dimg) * Tlen + t0) = pk;
            }
        }
        return;
    }

#pragma unroll
    for (int j = 0; j < 4; j++) {
        int col = n0 + wn * 64 + j * 16 + lm;
        float bv = bias[col];
#pragma unroll
        for (int i = 0; i < 4; i++) {
#pragma unroll
            for (int r = 0; r < 4; r++) {
                int row = m0 + wm * 64 + i * 16 + quad * 4 + r;
                float v = acc[i][j][r] + bv;
                if (ACT == 1) v = v / (1.f + __expf(-v));
                size_t idx = (size_t)row * N + col;
                if (ADD) v += Cf[idx];
                if (OUT_BF16) Cb[idx] = (bf16)v;
                else Cf[idx] = v;
            }
        }
    }
}

// ---------------- MFMA flash attention, barrier-free, XCD-swizzled, pipelined --------
// blockIdx = ((bh/8)*32 + (31-qt))*8 + (bh%8): all q-tiles of one (b,h) on one XCD
// (round-robin dispatch), keeping that head's K/Vt (~512 KB) L2-resident.
// V frags loaded at iteration top; next-iteration K frags prefetched after QK.
__global__ __launch_bounds__(256) void attn_mfma_kernel(const bf16* __restrict__ QKV,
                                                        const bf16* __restrict__ Vt,
                                                        bf16* __restrict__ Og, int T) {
    __shared__ __align__(16) bf16 Ps[4 * 16 * 64];  // 8 KB, XOR-swizzled P tiles
    const int ldq = 3 * D_MODEL;
    const int nqt = T / 64;
    int bidx = blockIdx.x;
    int c = bidx & 7;
    int rest = bidx >> 3;
    int qslot = rest % nqt;
    int bh = (rest / nqt) * 8 + c;
    int qt = (nqt - 1) - qslot;  // heavy tiles first within each XCD class
    int h = bh & (NUM_HEADS - 1), b = bh / NUM_HEADS;
    int tid = threadIdx.x;
    int w = tid >> 6, lane = tid & 63;
    int lm = lane & 15, quad = lane >> 4;
    int q0 = qt * 64, qrow0 = q0 + w * 16;

    // Q fragments (A-layout: m=lm, k=quad*8+j (+32))
    const bf16* Qp = QKV + ((size_t)(b * T + qrow0 + lm)) * ldq + h * HEAD_SIZE + quad * 8;
    bf16x8 qf0 = *(const bf16x8*)Qp;
    bf16x8 qf1 = *(const bf16x8*)(Qp + 32);

    const bf16* Kbase = QKV + ((size_t)b * T) * ldq + D_MODEL + h * HEAD_SIZE;
    const bf16* Vbase = Vt + ((size_t)b * D_MODEL + h * HEAD_SIZE) * T;

    f32x4 o[4];
    float m_i[4], l_i[4];
#pragma unroll
    for (int r = 0; r < 4; r++) {
        m_i[r] = -3.0e38f;
        l_i[r] = 0.f;
        o[r] = (f32x4){0.f, 0.f, 0.f, 0.f};
    }

    const float C = 0.1803368801111204f;  // 0.125 * log2(e)
    bf16* PsW = Ps + w * 16 * 64;
    int lm7 = lm & 7;

    // prologue: K frags for kt=0
    bf16x8 kcur[8];
#pragma unroll
    for (int jb = 0; jb < 4; jb++) {
        const bf16* kp = Kbase + (size_t)(jb * 16 + lm) * ldq + quad * 8;
        kcur[jb * 2]     = *(const bf16x8*)kp;
        kcur[jb * 2 + 1] = *(const bf16x8*)(kp + 32);
    }

    for (int kt = 0; kt <= qt; kt++) {
        int k0 = kt * 64;
        // ---- V frags early (in flight across QK + softmax) ----
        bf16x8 vv[8];
#pragma unroll
        for (int db = 0; db < 4; db++) {
            const bf16* vp = Vbase + (size_t)(db * 16 + lm) * T + k0 + quad * 8;
            vv[db * 2]     = *(const bf16x8*)vp;
            vv[db * 2 + 1] = *(const bf16x8*)(vp + 32);
        }
        // ---- S = Q K^T ----
        f32x4 s[4];
#pragma unroll
        for (int jb = 0; jb < 4; jb++) {
            f32x4 a = {0.f, 0.f, 0.f, 0.f};
            a = __builtin_amdgcn_mfma_f32_16x16x32_bf16(qf0, kcur[jb * 2], a, 0, 0, 0);
            a = __builtin_amdgcn_mfma_f32_16x16x32_bf16(qf1, kcur[jb * 2 + 1], a, 0, 0, 0);
            s[jb] = a;
        }
        // ---- prefetch next K (in flight across softmax + PV) ----
        bf16x8 knxt[8];
        if (kt < qt) {
#pragma unroll
            for (int jb = 0; jb < 4; jb++) {
                const bf16* kp = Kbase + (size_t)(k0 + 64 + jb * 16 + lm) * ldq + quad * 8;
                knxt[jb * 2]     = *(const bf16x8*)kp;
                knxt[jb * 2 + 1] = *(const bf16x8*)(kp + 32);
            }
        }
        // ---- causal mask ----
        if (kt == qt) {
#pragma unroll
            for (int jb = 0; jb < 4; jb++)
#pragma unroll
                for (int r = 0; r < 4; r++)
                    if (k0 + jb * 16 + lm > qrow0 + quad * 4 + r) s[jb][r] = -3.0e38f;
        }
        // ---- online softmax ----
#pragma unroll
        for (int r = 0; r < 4; r++) {
            float mn = fmaxf(fmaxf(s[0][r], s[1][r]), fmaxf(s[2][r], s[3][r]));
            mn = fmaxf(mn, __shfl_xor(mn, 1));
            mn = fmaxf(mn, __shfl_xor(mn, 2));
            mn = fmaxf(mn, __shfl_xor(mn, 4));
            mn = fmaxf(mn, __shfl_xor(mn, 8));
            float mt = fmaxf(m_i[r], mn);
            float alpha = exp2f((m_i[r] - mt) * C);
            m_i[r] = mt;
            float nb = -mt * C;
            float rs = 0.f;
#pragma unroll
            for (int jb = 0; jb < 4; jb++) {
                float p = exp2f(fmaf(s[jb][r], C, nb));
                s[jb][r] = p;
                rs += p;
            }
            rs += __shfl_xor(rs, 1);
            rs += __shfl_xor(rs, 2);
            rs += __shfl_xor(rs, 4);
            rs += __shfl_xor(rs, 8);
            l_i[r] = l_i[r] * alpha + rs;
#pragma unroll
            for (int db = 0; db < 4; db++) o[db][r] *= alpha;
        }
        // ---- P: C/D layout -> LDS (XOR swizzle) ----
#pragma unroll
        for (int jb = 0; jb < 4; jb++) {
            int g = jb * 2 + (lm >> 3);
#pragma unroll
            for (int r = 0; r < 4; r++) {
                int row = quad * 4 + r;
                PsW[row * 64 + ((g ^ (row & 7)) * 8) + lm7] = (bf16)s[jb][r];
            }
        }
        // ---- O += P V ----
        bf16x8 pf0 = *(const bf16x8*)&PsW[lm * 64 + ((quad ^ lm7) * 8)];
        bf16x8 pf1 = *(const bf16x8*)&PsW[lm * 64 + (((quad + 4) ^ lm7) * 8)];
#pragma unroll
        for (int db = 0; db < 4; db++) {
            o[db] = __builtin_amdgcn_mfma_f32_16x16x32_bf16(pf0, vv[db * 2], o[db], 0, 0, 0);
            o[db] = __builtin_amdgcn_mfma_f32_16x16x32_bf16(pf1, vv[db * 2 + 1], o[db], 0, 0, 0);
        }
        // ---- rotate K buffers ----
        if (kt < qt) {
#pragma unroll
            for (int q2 = 0; q2 < 8; q2++) kcur[q2] = knxt[q2];
        }
    }

    // ---- epilogue: O / l -> bf16 ----
    float inv[4];
#pragma unroll
    for (int r = 0; r < 4; r++) inv[r] = 1.f / l_i[r];
    bf16* Ob = Og + ((size_t)(b * T + qrow0 + quad * 4)) * D_MODEL + h * HEAD_SIZE + lm;
#pragma unroll
    for (int r = 0; r < 4; r++)
#pragma unroll
        for (int db = 0; db < 4; db++)
            Ob[(size_t)r * D_MODEL + db * 16] = (bf16)(o[db][r] * inv[r]);
}

extern "C" void kernel_launch(void* const* d_in, const int* in_sizes, int n_in,
                              void* d_out, int out_size, void* d_ws, size_t ws_size,
                              hipStream_t stream) {
    const float* x          = (const float*)d_in[0];
    const float* rms_scale  = (const float*)d_in[1];
    const float* in_proj_w  = (const float*)d_in[2];
    const float* in_proj_b  = (const float*)d_in[3];
    const float* out_proj_w = (const float*)d_in[4];
    const float* out_proj_b = (const float*)d_in[5];
    const float* w1         = (const float*)d_in[6];
    const float* b1         = (const float*)d_in[7];
    const float* w2         = (const float*)d_in[8];
    const float* b2         = (const float*)d_in[9];
    float* out = (float*)d_out;

    const int rows = in_sizes[0] / D_MODEL;  // 4096
    const int T = SEQ_T;
    const int B = rows / T;
    const int D = D_MODEL;

    bf16* inwb  = (bf16*)d_ws;                       // 3M
    bf16* outwb = inwb + (size_t)3 * D * D;          // 1M
    bf16* w1b   = outwb + (size_t)D * D;             // 4M
    bf16* w2b   = w1b + (size_t)4 * D * D;           // 4M
    bf16* XNb   = w2b + (size_t)4 * D * D;           // rows*D (reused as CTXb)
    bf16* RPb   = XNb + (size_t)rows * D;            // rows*D (reused as YNb)
    bf16* QKV   = RPb + (size_t)rows * D;            // rows*3D (H1b spans rows*4D)
    bf16* Vt    = QKV + (size_t)rows * 3 * D;        // rows*D  (tail of H1b region)
    bf16* CTXb  = XNb;
    bf16* YNb   = RPb;
    bf16* H1b   = QKV;

    // 0. cast weights to bf16
    {
        int n;
        n = 3 * D * D; cast_f32_bf16<<<(n / 4 + 255) / 256, 256, 0, stream>>>(in_proj_w, inwb, n);
        n = D * D;     cast_f32_bf16<<<(n / 4 + 255) / 256, 256, 0, stream>>>(out_proj_w, outwb, n);
        n = 4 * D * D; cast_f32_bf16<<<(n / 4 + 255) / 256, 256, 0, stream>>>(w1, w1b, n);
        n = 4 * D * D; cast_f32_bf16<<<(n / 4 + 255) / 256, 256, 0, stream>>>(w2, w2b, n);
    }
    // 1+2. fused rmsnorm + rope
    rmsnorm_rope_kernel<<<rows, 256, 0, stream>>>(x, rms_scale, XNb, RPb, T);
    // 3. fused QKV projection; Q/K -> QKV buffer, V -> Vt (transposed)
    {
        dim3 g(3 * D / 128, rows / 128);
        gemm_bf16<0, 0, 1, 1><<<g, 256, 0, stream>>>(RPb, XNb, 2 * D, inwb, in_proj_b,
                                                     nullptr, QKV, Vt, T, rows, 3 * D, D);
    }
    // 4. attention -> CTXb (bf16), XCD-swizzled grid
    attn_mfma_kernel<<<B * NUM_HEADS * (T / 64), 256, 0, stream>>>(QKV, Vt, CTXb, T);
    // 5. y = CTXb @ out_proj^T + b -> d_out (fp32)
    {
        dim3 g(D / 128, rows / 128);
        gemm_bf16<0, 0, 0, 0><<<g, 256, 0, stream>>>(CTXb, CTXb, D, outwb, out_proj_b,
                                                     out, nullptr, nullptr, 1, rows, D, D);
    }
    // 6. yn = rmsnorm(y) -> bf16
    rmsnorm_kernel<<<rows, 256, 0, stream>>>(out, rms_scale, YNb);
    // 7. H1b = silu(yn @ w1^T + b1) (bf16)
    {
        dim3 g(4 * D / 128, rows / 128);
        gemm_bf16<1, 0, 1, 0><<<g, 256, 0, stream>>>(YNb, YNb, 4 * D, w1b, b1,
                                                     nullptr, H1b, nullptr, 1, rows, 4 * D, D);
    }
    // 8. out += H1b @ w2^T + b2 (fp32 residual)
    {
        dim3 g(D / 128, rows / 128);
        gemm_bf16<0, 1, 0, 0><<<g, 256, 0, stream>>>(H1b, H1b, D, w2b, b2,
                                                     out, nullptr, nullptr, 1, rows, D, 4 * D);
    }
}

// Round 6
// 490.945 us; speedup vs baseline: 15.8454x; 1.1062x over previous
//
#include <hip/hip_runtime.h>
#include <math.h>
#include <stdint.h>

#define D_MODEL 1024
#define NUM_HEADS 16
#define HEAD_SIZE 64
#define SEQ_T 2048

typedef __bf16 bf16;
typedef __bf16 bf16x8 __attribute__((ext_vector_type(8)));
typedef float f32x4 __attribute__((ext_vector_type(4)));

__device__ __forceinline__ void gld_lds16(const bf16* g, bf16* l) {
    __builtin_amdgcn_global_load_lds(
        (__attribute__((address_space(1))) void*)(const_cast<bf16*>(g)),
        (__attribute__((address_space(3))) void*)(l), 16, 0, 0);
}

struct __align__(8) b4pack { bf16 v[4]; };

// ---------------- f32 -> bf16 cast (weights) ----------------
__global__ __launch_bounds__(256) void cast_f32_bf16(const float* __restrict__ src,
                                                     bf16* __restrict__ dst, int n) {
    int i = (blockIdx.x * 256 + threadIdx.x) * 4;
    if (i >= n) return;
    float4 v = *(const float4*)(src + i);
    b4pack o;
    o.v[0] = (bf16)v.x; o.v[1] = (bf16)v.y; o.v[2] = (bf16)v.z; o.v[3] = (bf16)v.w;
    *(b4pack*)(dst + i) = o;
}

// ---------------- fused RMSNorm + RoPE ----------------
__global__ __launch_bounds__(256) void rmsnorm_rope_kernel(const float* __restrict__ x,
                                                           const float* __restrict__ scale,
                                                           bf16* __restrict__ xn,
                                                           bf16* __restrict__ rp, int T) {
    __shared__ float red[4];
    int row = blockIdx.x;
    int t = row % T;
    const float* xp = x + (size_t)row * D_MODEL;
    int tid = threadIdx.x;
    float4 xv = *(const float4*)(xp + tid * 4);
    float s = xv.x * xv.x + xv.y * xv.y + xv.z * xv.z + xv.w * xv.w;
    for (int off = 32; off; off >>= 1) s += __shfl_down(s, off);
    if ((tid & 63) == 0) red[tid >> 6] = s;
    __syncthreads();
    if (tid == 0) red[0] = red[0] + red[1] + red[2] + red[3];
    __syncthreads();
    float inv = rsqrtf(red[0] * (1.0f / D_MODEL) + 1e-6f);
    float4 sc = *(const float4*)(scale + tid * 4);
    float n0 = xv.x * inv * sc.x, n1 = xv.y * inv * sc.y;
    float n2 = xv.z * inv * sc.z, n3 = xv.w * inv * sc.w;
    b4pack pn;
    pn.v[0] = (bf16)n0; pn.v[1] = (bf16)n1; pn.v[2] = (bf16)n2; pn.v[3] = (bf16)n3;
    *(b4pack*)(xn + (size_t)row * D_MODEL + tid * 4) = pn;
    int p0 = 2 * tid;
    float th0 = expf(-0.2878231366242557f * (float)(p0 & 31));        // ln(10000)/32
    float th1 = expf(-0.2878231366242557f * (float)((p0 + 1) & 31));
    float s0, c0, s1, c1;
    sincosf((float)t * th0, &s0, &c0);
    sincosf((float)t * th1, &s1, &c1);
    b4pack pr;
    pr.v[0] = (bf16)(n0 * c0 - n1 * s0);
    pr.v[1] = (bf16)(n1 * c0 + n0 * s0);
    pr.v[2] = (bf16)(n2 * c1 - n3 * s1);
    pr.v[3] = (bf16)(n3 * c1 + n2 * s1);
    *(b4pack*)(rp + (size_t)row * D_MODEL + tid * 4) = pr;
}

// ---------------- RMSNorm only ----------------
__global__ __launch_bounds__(256) void rmsnorm_kernel(const float* __restrict__ x,
                                                      const float* __restrict__ scale,
                                                      bf16* __restrict__ out) {
    __shared__ float red[4];
    int row = blockIdx.x;
    const float* xp = x + (size_t)row * D_MODEL;
    bf16* op = out + (size_t)row * D_MODEL;
    int tid = threadIdx.x;
    float s = 0.f;
    for (int i = tid; i < D_MODEL; i += 256) { float v = xp[i]; s += v * v; }
    for (int off = 32; off; off >>= 1) s += __shfl_down(s, off);
    if ((tid & 63) == 0) red[tid >> 6] = s;
    __syncthreads();
    if (tid == 0) red[0] = red[0] + red[1] + red[2] + red[3];
    __syncthreads();
    float inv = rsqrtf(red[0] * (1.0f / D_MODEL) + 1e-6f);
    for (int i = tid; i < D_MODEL; i += 256) op[i] = (bf16)(xp[i] * inv * scale[i]);
}

// ---------------- bf16 MFMA GEMM (m97 structure) ----------------
template <int ACT, int ADD, int OUT_BF16, int VT>
__global__ __launch_bounds__(256) void gemm_bf16(const bf16* __restrict__ A,
                                                 const bf16* __restrict__ A2, int splitN,
                                                 const bf16* __restrict__ W,
                                                 const float* __restrict__ bias,
                                                 float* __restrict__ Cf,
                                                 bf16* __restrict__ Cb,
                                                 bf16* __restrict__ Vtp, int Tlen,
                                                 int M, int N, int K) {
    __shared__ __align__(16) bf16 As[128 * 32];
    __shared__ __align__(16) bf16 Bs[128 * 32];
    int tid = threadIdx.x;
    int m0 = blockIdx.y * 128, n0 = blockIdx.x * 128;
    const bf16* Ag = (n0 < splitN) ? A : A2;

    int lane = tid & 63, w = tid >> 6;
    int wm = w >> 1, wn = w & 1;
    int lm = lane & 15, quad = lane >> 4;

    int c0 = tid, c1 = tid + 256;
    int ar0 = c0 >> 2, ak0 = (c0 & 3) * 8;
    int ar1 = c1 >> 2, ak1 = (c1 & 3) * 8;

    f32x4 acc[4][4];
#pragma unroll
    for (int i = 0; i < 4; i++)
#pragma unroll
        for (int j = 0; j < 4; j++)
#pragma unroll
            for (int r = 0; r < 4; r++) acc[i][j][r] = 0.f;

    int abase = (wm * 64 + lm) * 32 + quad * 8;
    int bbase = (wn * 64 + lm) * 32 + quad * 8;

    for (int k0 = 0; k0 < K; k0 += 32) {
        __syncthreads();
        gld_lds16(Ag + (size_t)(m0 + ar0) * K + k0 + ak0, As + c0 * 8);
        gld_lds16(Ag + (size_t)(m0 + ar1) * K + k0 + ak1, As + c1 * 8);
        gld_lds16(W  + (size_t)(n0 + ar0) * K + k0 + ak0, Bs + c0 * 8);
        gld_lds16(W  + (size_t)(n0 + ar1) * K + k0 + ak1, Bs + c1 * 8);
        __syncthreads();
        bf16x8 af[4], bfr[4];
#pragma unroll
        for (int i = 0; i < 4; i++) af[i] = *(const bf16x8*)&As[abase + i * 16 * 32];
#pragma unroll
        for (int j = 0; j < 4; j++) bfr[j] = *(const bf16x8*)&Bs[bbase + j * 16 * 32];
#pragma unroll
        for (int i = 0; i < 4; i++)
#pragma unroll
            for (int j = 0; j < 4; j++)
                acc[i][j] = __builtin_amdgcn_mfma_f32_16x16x32_bf16(af[i], bfr[j], acc[i][j], 0, 0, 0);
    }

    if (VT && n0 >= 2 * D_MODEL) {
#pragma unroll
        for (int j = 0; j < 4; j++) {
            int col = n0 + wn * 64 + j * 16 + lm;
            int dimg = col - 2 * D_MODEL;
            float bv = bias[col];
#pragma unroll
            for (int i = 0; i < 4; i++) {
                int row0 = m0 + wm * 64 + i * 16 + quad * 4;
                int bb = row0 / Tlen, t0 = row0 % Tlen;
                b4pack pk;
#pragma unroll
                for (int r = 0; r < 4; r++) pk.v[r] = (bf16)(acc[i][j][r] + bv);
                *(b4pack*)(Vtp + ((size_t)bb * D_MODEL + dimg) * Tlen + t0) = pk;
            }
        }
        return;
    }

#pragma unroll
    for (int j = 0; j < 4; j++) {
        int col = n0 + wn * 64 + j * 16 + lm;
        float bv = bias[col];
#pragma unroll
        for (int i = 0; i < 4; i++) {
#pragma unroll
            for (int r = 0; r < 4; r++) {
                int row = m0 + wm * 64 + i * 16 + quad * 4 + r;
                float v = acc[i][j][r] + bv;
                if (ACT == 1) v = v / (1.f + __expf(-v));
                size_t idx = (size_t)row * N + col;
                if (ADD) v += Cf[idx];
                if (OUT_BF16) Cb[idx] = (bf16)v;
                else Cf[idx] = v;
            }
        }
    }
}

// ---------------- MFMA flash attention, balanced persistent pairing ----------------
// Each block handles TWO q-tiles {31-pair, pair} of one (b,h): exactly 33 k-tile
// iterations per block -> all 512 blocks equal work, 2 blocks/CU steady.
// idx = ((bh>>3)*16 + pair)*8 + (bh&7): all blocks of one bh on one XCD
// (round-robin dispatch), K/Vt per XCD ~2 MB -> L2-resident.
__global__ __launch_bounds__(256) void attn_mfma_kernel(const bf16* __restrict__ QKV,
                                                        const bf16* __restrict__ Vt,
                                                        bf16* __restrict__ Og, int T) {
    __shared__ __align__(16) bf16 Ps[4 * 16 * 64];  // 8 KB, XOR-swizzled P tiles
    const int ldq = 3 * D_MODEL;
    const int nqt = T / 64;  // 32
    int bidx = blockIdx.x;
    int c = bidx & 7;
    int rest = bidx >> 3;
    int pair = rest & 15;
    int bh = (rest >> 4) * 8 + c;
    int h = bh & (NUM_HEADS - 1), b = bh / NUM_HEADS;
    int tid = threadIdx.x;
    int w = tid >> 6, lane = tid & 63;
    int lm = lane & 15, quad = lane >> 4;

    const bf16* Kbase = QKV + ((size_t)b * T) * ldq + D_MODEL + h * HEAD_SIZE;
    const bf16* Vbase = Vt + ((size_t)b * D_MODEL + h * HEAD_SIZE) * T;
    const float C = 0.1803368801111204f;  // 0.125 * log2(e)
    bf16* PsW = Ps + w * 16 * 64;
    int lm7 = lm & 7;

    for (int half = 0; half < 2; half++) {
        int qt = half ? pair : (nqt - 1 - pair);
        int q0 = qt * 64, qrow0 = q0 + w * 16;

        const bf16* Qp = QKV + ((size_t)(b * T + qrow0 + lm)) * ldq + h * HEAD_SIZE + quad * 8;
        bf16x8 qf0 = *(const bf16x8*)Qp;
        bf16x8 qf1 = *(const bf16x8*)(Qp + 32);

        f32x4 o[4];
        float m_i[4], l_i[4];
#pragma unroll
        for (int r = 0; r < 4; r++) {
            m_i[r] = -3.0e38f;
            l_i[r] = 0.f;
            o[r] = (f32x4){0.f, 0.f, 0.f, 0.f};
        }

        // prologue: K frags for kt=0
        bf16x8 kcur[8];
#pragma unroll
        for (int jb = 0; jb < 4; jb++) {
            const bf16* kp = Kbase + (size_t)(jb * 16 + lm) * ldq + quad * 8;
            kcur[jb * 2]     = *(const bf16x8*)kp;
            kcur[jb * 2 + 1] = *(const bf16x8*)(kp + 32);
        }

        for (int kt = 0; kt <= qt; kt++) {
            int k0 = kt * 64;
            // V frags early (in flight across QK + softmax)
            bf16x8 vv[8];
#pragma unroll
            for (int db = 0; db < 4; db++) {
                const bf16* vp = Vbase + (size_t)(db * 16 + lm) * T + k0 + quad * 8;
                vv[db * 2]     = *(const bf16x8*)vp;
                vv[db * 2 + 1] = *(const bf16x8*)(vp + 32);
            }
            // S = Q K^T
            f32x4 s[4];
#pragma unroll
            for (int jb = 0; jb < 4; jb++) {
                f32x4 a = {0.f, 0.f, 0.f, 0.f};
                a = __builtin_amdgcn_mfma_f32_16x16x32_bf16(qf0, kcur[jb * 2], a, 0, 0, 0);
                a = __builtin_amdgcn_mfma_f32_16x16x32_bf16(qf1, kcur[jb * 2 + 1], a, 0, 0, 0);
                s[jb] = a;
            }
            // prefetch next K (in flight across softmax + PV)
            bf16x8 knxt[8];
            if (kt < qt) {
#pragma unroll
                for (int jb = 0; jb < 4; jb++) {
                    const bf16* kp = Kbase + (size_t)(k0 + 64 + jb * 16 + lm) * ldq + quad * 8;
                    knxt[jb * 2]     = *(const bf16x8*)kp;
                    knxt[jb * 2 + 1] = *(const bf16x8*)(kp + 32);
                }
            }
            // causal mask
            if (kt == qt) {
#pragma unroll
                for (int jb = 0; jb < 4; jb++)
#pragma unroll
                    for (int r = 0; r < 4; r++)
                        if (k0 + jb * 16 + lm > qrow0 + quad * 4 + r) s[jb][r] = -3.0e38f;
            }
            // online softmax
#pragma unroll
            for (int r = 0; r < 4; r++) {
                float mn = fmaxf(fmaxf(s[0][r], s[1][r]), fmaxf(s[2][r], s[3][r]));
                mn = fmaxf(mn, __shfl_xor(mn, 1));
                mn = fmaxf(mn, __shfl_xor(mn, 2));
                mn = fmaxf(mn, __shfl_xor(mn, 4));
                mn = fmaxf(mn, __shfl_xor(mn, 8));
                float mt = fmaxf(m_i[r], mn);
                float alpha = exp2f((m_i[r] - mt) * C);
                m_i[r] = mt;
                float nb = -mt * C;
                float rs = 0.f;
#pragma unroll
                for (int jb = 0; jb < 4; jb++) {
                    float p = exp2f(fmaf(s[jb][r], C, nb));
                    s[jb][r] = p;
                    rs += p;
                }
                rs += __shfl_xor(rs, 1);
                rs += __shfl_xor(rs, 2);
                rs += __shfl_xor(rs, 4);
                rs += __shfl_xor(rs, 8);
                l_i[r] = l_i[r] * alpha + rs;
#pragma unroll
                for (int db = 0; db < 4; db++) o[db][r] *= alpha;
            }
            // P: C/D layout -> LDS (XOR swizzle)
#pragma unroll
            for (int jb = 0; jb < 4; jb++) {
                int g = jb * 2 + (lm >> 3);
#pragma unroll
                for (int r = 0; r < 4; r++) {
                    int row = quad * 4 + r;
                    PsW[row * 64 + ((g ^ (row & 7)) * 8) + lm7] = (bf16)s[jb][r];
                }
            }
            // O += P V
            bf16x8 pf0 = *(const bf16x8*)&PsW[lm * 64 + ((quad ^ lm7) * 8)];
            bf16x8 pf1 = *(const bf16x8*)&PsW[lm * 64 + (((quad + 4) ^ lm7) * 8)];
#pragma unroll
            for (int db = 0; db < 4; db++) {
                o[db] = __builtin_amdgcn_mfma_f32_16x16x32_bf16(pf0, vv[db * 2], o[db], 0, 0, 0);
                o[db] = __builtin_amdgcn_mfma_f32_16x16x32_bf16(pf1, vv[db * 2 + 1], o[db], 0, 0, 0);
            }
            // rotate K buffers
            if (kt < qt) {
#pragma unroll
                for (int q2 = 0; q2 < 8; q2++) kcur[q2] = knxt[q2];
            }
        }

        // epilogue: O / l -> bf16
        float inv[4];
#pragma unroll
        for (int r = 0; r < 4; r++) inv[r] = 1.f / l_i[r];
        bf16* Ob = Og + ((size_t)(b * T + qrow0 + quad * 4)) * D_MODEL + h * HEAD_SIZE + lm;
#pragma unroll
        for (int r = 0; r < 4; r++)
#pragma unroll
            for (int db = 0; db < 4; db++)
                Ob[(size_t)r * D_MODEL + db * 16] = (bf16)(o[db][r] * inv[r]);
    }
}

extern "C" void kernel_launch(void* const* d_in, const int* in_sizes, int n_in,
                              void* d_out, int out_size, void* d_ws, size_t ws_size,
                              hipStream_t stream) {
    const float* x          = (const float*)d_in[0];
    const float* rms_scale  = (const float*)d_in[1];
    const float* in_proj_w  = (const float*)d_in[2];
    const float* in_proj_b  = (const float*)d_in[3];
    const float* out_proj_w = (const float*)d_in[4];
    const float* out_proj_b = (const float*)d_in[5];
    const float* w1         = (const float*)d_in[6];
    const float* b1         = (const float*)d_in[7];
    const float* w2         = (const float*)d_in[8];
    const float* b2         = (const float*)d_in[9];
    float* out = (float*)d_out;

    const int rows = in_sizes[0] / D_MODEL;  // 4096
    const int T = SEQ_T;
    const int B = rows / T;
    const int D = D_MODEL;

    bf16* inwb  = (bf16*)d_ws;                       // 3M
    bf16* outwb = inwb + (size_t)3 * D * D;          // 1M
    bf16* w1b   = outwb + (size_t)D * D;             // 4M
    bf16* w2b   = w1b + (size_t)4 * D * D;           // 4M
    bf16* XNb   = w2b + (size_t)4 * D * D;           // rows*D (reused as CTXb)
    bf16* RPb   = XNb + (size_t)rows * D;            // rows*D (reused as YNb)
    bf16* QKV   = RPb + (size_t)rows * D;            // rows*3D (H1b spans rows*4D)
    bf16* Vt    = QKV + (size_t)rows * 3 * D;        // rows*D  (tail of H1b region)
    bf16* CTXb  = XNb;
    bf16* YNb   = RPb;
    bf16* H1b   = QKV;

    // 0. cast weights to bf16
    {
        int n;
        n = 3 * D * D; cast_f32_bf16<<<(n / 4 + 255) / 256, 256, 0, stream>>>(in_proj_w, inwb, n);
        n = D * D;     cast_f32_bf16<<<(n / 4 + 255) / 256, 256, 0, stream>>>(out_proj_w, outwb, n);
        n = 4 * D * D; cast_f32_bf16<<<(n / 4 + 255) / 256, 256, 0, stream>>>(w1, w1b, n);
        n = 4 * D * D; cast_f32_bf16<<<(n / 4 + 255) / 256, 256, 0, stream>>>(w2, w2b, n);
    }
    // 1+2. fused rmsnorm + rope
    rmsnorm_rope_kernel<<<rows, 256, 0, stream>>>(x, rms_scale, XNb, RPb, T);
    // 3. fused QKV projection; Q/K -> QKV buffer, V -> Vt (transposed)
    {
        dim3 g(3 * D / 128, rows / 128);
        gemm_bf16<0, 0, 1, 1><<<g, 256, 0, stream>>>(RPb, XNb, 2 * D, inwb, in_proj_b,
                                                     nullptr, QKV, Vt, T, rows, 3 * D, D);
    }
    // 4. attention -> CTXb (bf16), balanced pairing, 512 blocks
    attn_mfma_kernel<<<B * NUM_HEADS * (T / 128), 256, 0, stream>>>(QKV, Vt, CTXb, T);
    // 5. y = CTXb @ out_proj^T + b -> d_out (fp32)
    {
        dim3 g(D / 128, rows / 128);
        gemm_bf16<0, 0, 0, 0><<<g, 256, 0, stream>>>(CTXb, CTXb, D, outwb, out_proj_b,
                                                     out, nullptr, nullptr, 1, rows, D, D);
    }
    // 6. yn = rmsnorm(y) -> bf16
    rmsnorm_kernel<<<rows, 256, 0, stream>>>(out, rms_scale, YNb);
    // 7. H1b = silu(yn @ w1^T + b1) (bf16)
    {
        dim3 g(4 * D / 128, rows / 128);
        gemm_bf16<1, 0, 1, 0><<<g, 256, 0, stream>>>(YNb, YNb, 4 * D, w1b, b1,
                                                     nullptr, H1b, nullptr, 1, rows, 4 * D, D);
    }
    // 8. out += H1b @ w2^T + b2 (fp32 residual)
    {
        dim3 g(D / 128, rows / 128);
        gemm_bf16<0, 1, 0, 0><<<g, 256, 0, stream>>>(H1b, H1b, D, w2b, b2,
                                                     out, nullptr, nullptr, 1, rows, D, 4 * D);
    }
}

// Round 7
// 477.481 us; speedup vs baseline: 16.2922x; 1.0282x over previous
//
#include <hip/hip_runtime.h>
#include <math.h>
#include <stdint.h>

#define D_MODEL 1024
#define NUM_HEADS 16
#define HEAD_SIZE 64
#define SEQ_T 2048

typedef __bf16 bf16;
typedef __bf16 bf16x8 __attribute__((ext_vector_type(8)));
typedef float f32x4 __attribute__((ext_vector_type(4)));

__device__ __forceinline__ void gld_lds16(const bf16* g, bf16* l) {
    __builtin_amdgcn_global_load_lds(
        (__attribute__((address_space(1))) void*)(const_cast<bf16*>(g)),
        (__attribute__((address_space(3))) void*)(l), 16, 0, 0);
}

struct __align__(8) b4pack { bf16 v[4]; };

// ---------------- fused f32 -> bf16 cast of all 4 weight matrices ----------------
__global__ __launch_bounds__(256) void cast_all_weights(const float* __restrict__ s0, bf16* __restrict__ d0, int n0,
                                                        const float* __restrict__ s1, bf16* __restrict__ d1, int n1,
                                                        const float* __restrict__ s2, bf16* __restrict__ d2, int n2,
                                                        const float* __restrict__ s3, bf16* __restrict__ d3, int n3) {
    int i = (blockIdx.x * 256 + threadIdx.x) * 4;
    const float* src;
    bf16* dst;
    if (i < n0) { src = s0; dst = d0; }
    else if (i < n0 + n1) { i -= n0; src = s1; dst = d1; }
    else if (i < n0 + n1 + n2) { i -= n0 + n1; src = s2; dst = d2; }
    else { i -= n0 + n1 + n2; if (i >= n3) return; src = s3; dst = d3; }
    float4 v = *(const float4*)(src + i);
    b4pack o;
    o.v[0] = (bf16)v.x; o.v[1] = (bf16)v.y; o.v[2] = (bf16)v.z; o.v[3] = (bf16)v.w;
    *(b4pack*)(dst + i) = o;
}

// ---------------- fused RMSNorm + RoPE ----------------
__global__ __launch_bounds__(256) void rmsnorm_rope_kernel(const float* __restrict__ x,
                                                           const float* __restrict__ scale,
                                                           bf16* __restrict__ xn,
                                                           bf16* __restrict__ rp, int T) {
    __shared__ float red[4];
    int row = blockIdx.x;
    int t = row % T;
    const float* xp = x + (size_t)row * D_MODEL;
    int tid = threadIdx.x;
    float4 xv = *(const float4*)(xp + tid * 4);
    float s = xv.x * xv.x + xv.y * xv.y + xv.z * xv.z + xv.w * xv.w;
    for (int off = 32; off; off >>= 1) s += __shfl_down(s, off);
    if ((tid & 63) == 0) red[tid >> 6] = s;
    __syncthreads();
    if (tid == 0) red[0] = red[0] + red[1] + red[2] + red[3];
    __syncthreads();
    float inv = rsqrtf(red[0] * (1.0f / D_MODEL) + 1e-6f);
    float4 sc = *(const float4*)(scale + tid * 4);
    float n0 = xv.x * inv * sc.x, n1 = xv.y * inv * sc.y;
    float n2 = xv.z * inv * sc.z, n3 = xv.w * inv * sc.w;
    b4pack pn;
    pn.v[0] = (bf16)n0; pn.v[1] = (bf16)n1; pn.v[2] = (bf16)n2; pn.v[3] = (bf16)n3;
    *(b4pack*)(xn + (size_t)row * D_MODEL + tid * 4) = pn;
    int p0 = 2 * tid;
    float th0 = expf(-0.2878231366242557f * (float)(p0 & 31));        // ln(10000)/32
    float th1 = expf(-0.2878231366242557f * (float)((p0 + 1) & 31));
    float s0, c0, s1, c1;
    sincosf((float)t * th0, &s0, &c0);
    sincosf((float)t * th1, &s1, &c1);
    b4pack pr;
    pr.v[0] = (bf16)(n0 * c0 - n1 * s0);
    pr.v[1] = (bf16)(n1 * c0 + n0 * s0);
    pr.v[2] = (bf16)(n2 * c1 - n3 * s1);
    pr.v[3] = (bf16)(n3 * c1 + n2 * s1);
    *(b4pack*)(rp + (size_t)row * D_MODEL + tid * 4) = pr;
}

// ---------------- RMSNorm only ----------------
__global__ __launch_bounds__(256) void rmsnorm_kernel(const float* __restrict__ x,
                                                      const float* __restrict__ scale,
                                                      bf16* __restrict__ out) {
    __shared__ float red[4];
    int row = blockIdx.x;
    const float* xp = x + (size_t)row * D_MODEL;
    bf16* op = out + (size_t)row * D_MODEL;
    int tid = threadIdx.x;
    float s = 0.f;
    for (int i = tid; i < D_MODEL; i += 256) { float v = xp[i]; s += v * v; }
    for (int off = 32; off; off >>= 1) s += __shfl_down(s, off);
    if ((tid & 63) == 0) red[tid >> 6] = s;
    __syncthreads();
    if (tid == 0) red[0] = red[0] + red[1] + red[2] + red[3];
    __syncthreads();
    float inv = rsqrtf(red[0] * (1.0f / D_MODEL) + 1e-6f);
    for (int i = tid; i < D_MODEL; i += 256) op[i] = (bf16)(xp[i] * inv * scale[i]);
}

// ---------------- bf16 MFMA GEMM, 128x128 tile (m97 structure) ----------------
template <int ACT, int ADD, int OUT_BF16, int VT>
__global__ __launch_bounds__(256) void gemm_bf16(const bf16* __restrict__ A,
                                                 const bf16* __restrict__ A2, int splitN,
                                                 const bf16* __restrict__ W,
                                                 const float* __restrict__ bias,
                                                 float* __restrict__ Cf,
                                                 bf16* __restrict__ Cb,
                                                 bf16* __restrict__ Vtp, int Tlen,
                                                 int M, int N, int K) {
    __shared__ __align__(16) bf16 As[128 * 32];
    __shared__ __align__(16) bf16 Bs[128 * 32];
    int tid = threadIdx.x;
    int m0 = blockIdx.y * 128, n0 = blockIdx.x * 128;
    const bf16* Ag = (n0 < splitN) ? A : A2;

    int lane = tid & 63, w = tid >> 6;
    int wm = w >> 1, wn = w & 1;
    int lm = lane & 15, quad = lane >> 4;

    int c0 = tid, c1 = tid + 256;
    int ar0 = c0 >> 2, ak0 = (c0 & 3) * 8;
    int ar1 = c1 >> 2, ak1 = (c1 & 3) * 8;

    f32x4 acc[4][4];
#pragma unroll
    for (int i = 0; i < 4; i++)
#pragma unroll
        for (int j = 0; j < 4; j++)
#pragma unroll
            for (int r = 0; r < 4; r++) acc[i][j][r] = 0.f;

    int abase = (wm * 64 + lm) * 32 + quad * 8;
    int bbase = (wn * 64 + lm) * 32 + quad * 8;

    for (int k0 = 0; k0 < K; k0 += 32) {
        __syncthreads();
        gld_lds16(Ag + (size_t)(m0 + ar0) * K + k0 + ak0, As + c0 * 8);
        gld_lds16(Ag + (size_t)(m0 + ar1) * K + k0 + ak1, As + c1 * 8);
        gld_lds16(W  + (size_t)(n0 + ar0) * K + k0 + ak0, Bs + c0 * 8);
        gld_lds16(W  + (size_t)(n0 + ar1) * K + k0 + ak1, Bs + c1 * 8);
        __syncthreads();
        bf16x8 af[4], bfr[4];
#pragma unroll
        for (int i = 0; i < 4; i++) af[i] = *(const bf16x8*)&As[abase + i * 16 * 32];
#pragma unroll
        for (int j = 0; j < 4; j++) bfr[j] = *(const bf16x8*)&Bs[bbase + j * 16 * 32];
#pragma unroll
        for (int i = 0; i < 4; i++)
#pragma unroll
            for (int j = 0; j < 4; j++)
                acc[i][j] = __builtin_amdgcn_mfma_f32_16x16x32_bf16(af[i], bfr[j], acc[i][j], 0, 0, 0);
    }

    if (VT && n0 >= 2 * D_MODEL) {
#pragma unroll
        for (int j = 0; j < 4; j++) {
            int col = n0 + wn * 64 + j * 16 + lm;
            int dimg = col - 2 * D_MODEL;
            float bv = bias[col];
#pragma unroll
            for (int i = 0; i < 4; i++) {
                int row0 = m0 + wm * 64 + i * 16 + quad * 4;
                int bb = row0 / Tlen, t0 = row0 % Tlen;
                b4pack pk;
#pragma unroll
                for (int r = 0; r < 4; r++) pk.v[r] = (bf16)(acc[i][j][r] + bv);
                *(b4pack*)(Vtp + ((size_t)bb * D_MODEL + dimg) * Tlen + t0) = pk;
            }
        }
        return;
    }

#pragma unroll
    for (int j = 0; j < 4; j++) {
        int col = n0 + wn * 64 + j * 16 + lm;
        float bv = bias[col];
#pragma unroll
        for (int i = 0; i < 4; i++) {
#pragma unroll
            for (int r = 0; r < 4; r++) {
                int row = m0 + wm * 64 + i * 16 + quad * 4 + r;
                float v = acc[i][j][r] + bv;
                if (ACT == 1) v = v / (1.f + __expf(-v));
                size_t idx = (size_t)row * N + col;
                if (ADD) v += Cf[idx];
                if (OUT_BF16) Cb[idx] = (bf16)v;
                else Cf[idx] = v;
            }
        }
    }
}

// ---------------- skinny bf16 MFMA GEMM, 64x128 tile (for N=1024 GEMMs) -------------
// 2x the blocks of the 128-tile at these shapes -> 2 blocks/CU instead of 1.
template <int ADD>
__global__ __launch_bounds__(256) void gemm_bf16_skinny(const bf16* __restrict__ A,
                                                        const bf16* __restrict__ W,
                                                        const float* __restrict__ bias,
                                                        float* __restrict__ Cf,
                                                        int M, int N, int K) {
    __shared__ __align__(16) bf16 As[64 * 32];   // 4 KB
    __shared__ __align__(16) bf16 Bs[128 * 32];  // 8 KB
    int tid = threadIdx.x;
    int m0 = blockIdx.y * 64, n0 = blockIdx.x * 128;

    int lane = tid & 63, w = tid >> 6;
    int lm = lane & 15, quad = lane >> 4;

    int ar = tid >> 2, ak = (tid & 3) * 8;         // A: 256 chunks
    int c1 = tid + 256;
    int br1 = c1 >> 2, bk1 = (c1 & 3) * 8;         // B: 512 chunks

    f32x4 acc[8];
#pragma unroll
    for (int j = 0; j < 8; j++)
#pragma unroll
        for (int r = 0; r < 4; r++) acc[j][r] = 0.f;

    int abase = (w * 16 + lm) * 32 + quad * 8;
    int bbase = lm * 32 + quad * 8;

    for (int k0 = 0; k0 < K; k0 += 32) {
        __syncthreads();
        gld_lds16(A + (size_t)(m0 + ar) * K + k0 + ak, As + tid * 8);
        gld_lds16(W + (size_t)(n0 + ar) * K + k0 + ak, Bs + tid * 8);
        gld_lds16(W + (size_t)(n0 + br1) * K + k0 + bk1, Bs + c1 * 8);
        __syncthreads();
        bf16x8 af = *(const bf16x8*)&As[abase];
#pragma unroll
        for (int j = 0; j < 8; j++) {
            bf16x8 bfr = *(const bf16x8*)&Bs[bbase + j * 16 * 32];
            acc[j] = __builtin_amdgcn_mfma_f32_16x16x32_bf16(af, bfr, acc[j], 0, 0, 0);
        }
    }

#pragma unroll
    for (int j = 0; j < 8; j++) {
        int col = n0 + j * 16 + lm;
        float bv = bias[col];
#pragma unroll
        for (int r = 0; r < 4; r++) {
            int row = m0 + w * 16 + quad * 4 + r;
            float v = acc[j][r] + bv;
            size_t idx = (size_t)row * N + col;
            if (ADD) v += Cf[idx];
            Cf[idx] = v;
        }
    }
}

// ---------------- MFMA flash attention: 1-wave blocks, 16-row q-slices ----------------
// grid = B*H*(T/16) = 4096 blocks x 64 threads -> 16 blocks/CU, 4 waves/SIMD.
// No cross-wave coupling at all. idx low 3 bits = bh%8 (XCD class); within a
// class, slices descend (heavy first) and greedy dispatch balances the load.
__global__ __launch_bounds__(64) void attn_mfma_kernel(const bf16* __restrict__ QKV,
                                                       const bf16* __restrict__ Vt,
                                                       bf16* __restrict__ Og, int T) {
    __shared__ __align__(16) bf16 Ps[16 * 64];  // 2 KB
    const int ldq = 3 * D_MODEL;
    const int nsl = T / 16;  // 128 slices per bh
    int bidx = blockIdx.x;
    int c = bidx & 7;
    int rest = bidx >> 3;
    int qslot = rest & (nsl - 1);
    int bh = (rest >> 7) * 8 + c;
    int qs = (nsl - 1) - qslot;          // heavy slices first
    int h = bh & (NUM_HEADS - 1), b = bh / NUM_HEADS;
    int lane = threadIdx.x & 63;
    int lm = lane & 15, quad = lane >> 4;
    int qrow0 = qs * 16;
    int nkt = (qs >> 2) + 1;             // causal k-tiles of 64

    const bf16* Qp = QKV + ((size_t)(b * T + qrow0 + lm)) * ldq + h * HEAD_SIZE + quad * 8;
    bf16x8 qf0 = *(const bf16x8*)Qp;
    bf16x8 qf1 = *(const bf16x8*)(Qp + 32);

    const bf16* Kbase = QKV + ((size_t)b * T) * ldq + D_MODEL + h * HEAD_SIZE;
    const bf16* Vbase = Vt + ((size_t)b * D_MODEL + h * HEAD_SIZE) * T;
    const float C = 0.1803368801111204f;  // 0.125 * log2(e)
    int lm7 = lm & 7;

    f32x4 o[4];
    float m_i[4], l_i[4];
#pragma unroll
    for (int r = 0; r < 4; r++) {
        m_i[r] = -3.0e38f;
        l_i[r] = 0.f;
        o[r] = (f32x4){0.f, 0.f, 0.f, 0.f};
    }

    // prologue: K frags for kt=0
    bf16x8 kcur[8];
#pragma unroll
    for (int jb = 0; jb < 4; jb++) {
        const bf16* kp = Kbase + (size_t)(jb * 16 + lm) * ldq + quad * 8;
        kcur[jb * 2]     = *(const bf16x8*)kp;
        kcur[jb * 2 + 1] = *(const bf16x8*)(kp + 32);
    }

    for (int kt = 0; kt < nkt; kt++) {
        int k0 = kt * 64;
        // V frags early (in flight across QK + softmax)
        bf16x8 vv[8];
#pragma unroll
        for (int db = 0; db < 4; db++) {
            const bf16* vp = Vbase + (size_t)(db * 16 + lm) * T + k0 + quad * 8;
            vv[db * 2]     = *(const bf16x8*)vp;
            vv[db * 2 + 1] = *(const bf16x8*)(vp + 32);
        }
        // S = Q K^T
        f32x4 s[4];
#pragma unroll
        for (int jb = 0; jb < 4; jb++) {
            f32x4 a = {0.f, 0.f, 0.f, 0.f};
            a = __builtin_amdgcn_mfma_f32_16x16x32_bf16(qf0, kcur[jb * 2], a, 0, 0, 0);
            a = __builtin_amdgcn_mfma_f32_16x16x32_bf16(qf1, kcur[jb * 2 + 1], a, 0, 0, 0);
            s[jb] = a;
        }
        // prefetch next K
        bf16x8 knxt[8];
        if (kt + 1 < nkt) {
#pragma unroll
            for (int jb = 0; jb < 4; jb++) {
                const bf16* kp = Kbase + (size_t)(k0 + 64 + jb * 16 + lm) * ldq + quad * 8;
                knxt[jb * 2]     = *(const bf16x8*)kp;
                knxt[jb * 2 + 1] = *(const bf16x8*)(kp + 32);
            }
        }
        // causal mask (last tile only)
        if (kt + 1 == nkt) {
#pragma unroll
            for (int jb = 0; jb < 4; jb++)
#pragma unroll
                for (int r = 0; r < 4; r++)
                    if (k0 + jb * 16 + lm > qrow0 + quad * 4 + r) s[jb][r] = -3.0e38f;
        }
        // online softmax
#pragma unroll
        for (int r = 0; r < 4; r++) {
            float mn = fmaxf(fmaxf(s[0][r], s[1][r]), fmaxf(s[2][r], s[3][r]));
            mn = fmaxf(mn, __shfl_xor(mn, 1));
            mn = fmaxf(mn, __shfl_xor(mn, 2));
            mn = fmaxf(mn, __shfl_xor(mn, 4));
            mn = fmaxf(mn, __shfl_xor(mn, 8));
            float mt = fmaxf(m_i[r], mn);
            float alpha = exp2f((m_i[r] - mt) * C);
            m_i[r] = mt;
            float nb = -mt * C;
            float rs = 0.f;
#pragma unroll
            for (int jb = 0; jb < 4; jb++) {
                float p = exp2f(fmaf(s[jb][r], C, nb));
                s[jb][r] = p;
                rs += p;
            }
            rs += __shfl_xor(rs, 1);
            rs += __shfl_xor(rs, 2);
            rs += __shfl_xor(rs, 4);
            rs += __shfl_xor(rs, 8);
            l_i[r] = l_i[r] * alpha + rs;
#pragma unroll
            for (int db = 0; db < 4; db++) o[db][r] *= alpha;
        }
        // P: C/D layout -> LDS (XOR swizzle)
#pragma unroll
        for (int jb = 0; jb < 4; jb++) {
            int g = jb * 2 + (lm >> 3);
#pragma unroll
            for (int r = 0; r < 4; r++) {
                int row = quad * 4 + r;
                Ps[row * 64 + ((g ^ (row & 7)) * 8) + lm7] = (bf16)s[jb][r];
            }
        }
        // O += P V
        bf16x8 pf0 = *(const bf16x8*)&Ps[lm * 64 + ((quad ^ lm7) * 8)];
        bf16x8 pf1 = *(const bf16x8*)&Ps[lm * 64 + (((quad + 4) ^ lm7) * 8)];
#pragma unroll
        for (int db = 0; db < 4; db++) {
            o[db] = __builtin_amdgcn_mfma_f32_16x16x32_bf16(pf0, vv[db * 2], o[db], 0, 0, 0);
            o[db] = __builtin_amdgcn_mfma_f32_16x16x32_bf16(pf1, vv[db * 2 + 1], o[db], 0, 0, 0);
        }
        // rotate K buffers
        if (kt + 1 < nkt) {
#pragma unroll
            for (int q2 = 0; q2 < 8; q2++) kcur[q2] = knxt[q2];
        }
    }

    // epilogue: O / l -> bf16
    float inv[4];
#pragma unroll
    for (int r = 0; r < 4; r++) inv[r] = 1.f / l_i[r];
    bf16* Ob = Og + ((size_t)(b * T + qrow0 + quad * 4)) * D_MODEL + h * HEAD_SIZE + lm;
#pragma unroll
    for (int r = 0; r < 4; r++)
#pragma unroll
        for (int db = 0; db < 4; db++)
            Ob[(size_t)r * D_MODEL + db * 16] = (bf16)(o[db][r] * inv[r]);
}

extern "C" void kernel_launch(void* const* d_in, const int* in_sizes, int n_in,
                              void* d_out, int out_size, void* d_ws, size_t ws_size,
                              hipStream_t stream) {
    const float* x          = (const float*)d_in[0];
    const float* rms_scale  = (const float*)d_in[1];
    const float* in_proj_w  = (const float*)d_in[2];
    const float* in_proj_b  = (const float*)d_in[3];
    const float* out_proj_w = (const float*)d_in[4];
    const float* out_proj_b = (const float*)d_in[5];
    const float* w1         = (const float*)d_in[6];
    const float* b1         = (const float*)d_in[7];
    const float* w2         = (const float*)d_in[8];
    const float* b2         = (const float*)d_in[9];
    float* out = (float*)d_out;

    const int rows = in_sizes[0] / D_MODEL;  // 4096
    const int T = SEQ_T;
    const int B = rows / T;
    const int D = D_MODEL;

    bf16* inwb  = (bf16*)d_ws;                       // 3M
    bf16* outwb = inwb + (size_t)3 * D * D;          // 1M
    bf16* w1b   = outwb + (size_t)D * D;             // 4M
    bf16* w2b   = w1b + (size_t)4 * D * D;           // 4M
    bf16* XNb   = w2b + (size_t)4 * D * D;           // rows*D (reused as CTXb)
    bf16* RPb   = XNb + (size_t)rows * D;            // rows*D (reused as YNb)
    bf16* QKV   = RPb + (size_t)rows * D;            // rows*3D (H1b spans rows*4D)
    bf16* Vt    = QKV + (size_t)rows * 3 * D;        // rows*D  (tail of H1b region)
    bf16* CTXb  = XNb;
    bf16* YNb   = RPb;
    bf16* H1b   = QKV;

    // 0. cast all weights to bf16 (one kernel)
    {
        int n0 = 3 * D * D, n1 = D * D, n2 = 4 * D * D, n3 = 4 * D * D;
        int tot4 = (n0 + n1 + n2 + n3) / 4;
        cast_all_weights<<<(tot4 + 255) / 256, 256, 0, stream>>>(
            in_proj_w, inwb, n0, out_proj_w, outwb, n1, w1, w1b, n2, w2, w2b, n3);
    }
    // 1+2. fused rmsnorm + rope
    rmsnorm_rope_kernel<<<rows, 256, 0, stream>>>(x, rms_scale, XNb, RPb, T);
    // 3. fused QKV projection; Q/K -> QKV buffer, V -> Vt (transposed)
    {
        dim3 g(3 * D / 128, rows / 128);
        gemm_bf16<0, 0, 1, 1><<<g, 256, 0, stream>>>(RPb, XNb, 2 * D, inwb, in_proj_b,
                                                     nullptr, QKV, Vt, T, rows, 3 * D, D);
    }
    // 4. attention -> CTXb (bf16): 4096 one-wave blocks
    attn_mfma_kernel<<<B * NUM_HEADS * (T / 16), 64, 0, stream>>>(QKV, Vt, CTXb, T);
    // 5. y = CTXb @ out_proj^T + b -> d_out (fp32), skinny tiles (512 blocks)
    {
        dim3 g(D / 128, rows / 64);
        gemm_bf16_skinny<0><<<g, 256, 0, stream>>>(CTXb, outwb, out_proj_b, out,
                                                   rows, D, D);
    }
    // 6. yn = rmsnorm(y) -> bf16
    rmsnorm_kernel<<<rows, 256, 0, stream>>>(out, rms_scale, YNb);
    // 7. H1b = silu(yn @ w1^T + b1) (bf16)
    {
        dim3 g(4 * D / 128, rows / 128);
        gemm_bf16<1, 0, 1, 0><<<g, 256, 0, stream>>>(YNb, YNb, 4 * D, w1b, b1,
                                                     nullptr, H1b, nullptr, 1, rows, 4 * D, D);
    }
    // 8. out += H1b @ w2^T + b2 (fp32 residual), skinny tiles (512 blocks)
    {
        dim3 g(D / 128, rows / 64);
        gemm_bf16_skinny<1><<<g, 256, 0, stream>>>(H1b, w2b, b2, out,
                                                   rows, D, 4 * D);
    }
}